// Round 8
// baseline (295.616 us; speedup 1.0000x reference)
//
#include <hip/hip_runtime.h>
#include <stdint.h>

#define L_DIM 1024
#define N_DIM 32
#define C_DIM 512
#define M_DIM (L_DIM * N_DIM)   // 32768 rows for the GEMMs
#define EPS_BN 1e-5f

typedef __attribute__((ext_vector_type(8))) short bf16x8;
typedef __attribute__((ext_vector_type(4))) float f32x4;

__device__ __forceinline__ unsigned short f2bf(float f) {
  union { float f; unsigned int u; } a; a.f = f;
  unsigned int u = a.u;
  return (unsigned short)((u + 0x7FFFu + ((u >> 16) & 1u)) >> 16); // RNE
}
__device__ __forceinline__ float bf2f(unsigned short h) {
  union { float f; unsigned int u; } a; a.u = ((unsigned int)h) << 16;
  return a.f;
}

__device__ __forceinline__ void gl16(const void* g, void* l) {
  __builtin_amdgcn_global_load_lds(
      (const __attribute__((address_space(1))) unsigned int*)g,
      (__attribute__((address_space(3))) unsigned int*)l, 16, 0, 0);
}

// ---------------- split fp32 -> bf16 hi/lo: x, W1, W2 in one kernel ----------------
__global__ void k_split_all(const float* __restrict__ x, const float* __restrict__ W1,
                            const float* __restrict__ W2,
                            unsigned short* __restrict__ Ahi, unsigned short* __restrict__ Alo,
                            unsigned short* __restrict__ W1hi, unsigned short* __restrict__ W1lo,
                            unsigned short* __restrict__ W2hi, unsigned short* __restrict__ W2lo) {
  const int NX = M_DIM * C_DIM / 4;      // 4,194,304 float4
  const int NW = C_DIM * C_DIM / 4;      // 65,536 float4
  int i = blockIdx.x * 256 + threadIdx.x;
  int stride = gridDim.x * 256;
  for (; i < NX + 2 * NW; i += stride) {
    const float4* src; unsigned short* dh; unsigned short* dl; int j;
    if (i < NX)            { src = (const float4*)x;  dh = Ahi;  dl = Alo;  j = i; }
    else if (i < NX + NW)  { src = (const float4*)W1; dh = W1hi; dl = W1lo; j = i - NX; }
    else                   { src = (const float4*)W2; dh = W2hi; dl = W2lo; j = i - NX - NW; }
    float4 v = src[j];
    ushort4 h, l;
    h.x = f2bf(v.x); l.x = f2bf(v.x - bf2f(h.x));
    h.y = f2bf(v.y); l.y = f2bf(v.y - bf2f(h.y));
    h.z = f2bf(v.z); l.z = f2bf(v.z - bf2f(h.z));
    h.w = f2bf(v.w); l.w = f2bf(v.w - bf2f(h.w));
    ((ushort4*)dh)[j] = h;
    ((ushort4*)dl)[j] = l;
  }
}

// ---------------- bf16x3 MFMA GEMM: C = A * B^T + bias, fused BN stats ----------------
// R5 structure (best validated): 256x256 tile, BK=32, 512 threads = 8 waves (2M x 4N),
// wave-tile 128x64, monolithic COMPUTE, 2 barriers + counted vmcnt(8) per K-step,
// double-buffered 128KB LDS, grid 256 = 1 block/CU, XCD swizzle.
__global__ __launch_bounds__(512, 2)
void k_gemm(const unsigned short* __restrict__ Ahi, const unsigned short* __restrict__ Alo,
            const unsigned short* __restrict__ Bhi, const unsigned short* __restrict__ Blo,
            const float* __restrict__ bias, float* __restrict__ C,
            float* __restrict__ gsum, float* __restrict__ gsq) {
  const int K = C_DIM;
  int d = blockIdx.x;
  int xcd = d & 7;
  int q = d >> 3;                  // 0..31
  int bm = xcd * 16 + (q >> 1);    // 0..127
  int bn = q & 1;                  // 0..1

  __shared__ unsigned short lds[2][32768];   // 128 KB total

  int tid  = threadIdx.x;
  int lane = tid & 63;
  int wave = tid >> 6;
  int wm = wave >> 2;              // 0..1
  int wn = wave & 3;               // 0..3
  int lr = lane & 15;
  int lk = lane >> 4;

  f32x4 acc[8][4];
#pragma unroll
  for (int i = 0; i < 8; ++i)
#pragma unroll
    for (int j = 0; j < 4; ++j) acc[i][j] = (f32x4){0.f, 0.f, 0.f, 0.f};

  const int ra0 = tid & 255, ka0 = (tid >> 8) & 3;
  const int ra1 = (tid + 512) & 255, ka1 = ((tid + 512) >> 8) & 3;
  const int oa0 = (bm * 256 + ra0) * K + ka0 * 8;
  const int oa1 = (bm * 256 + ra1) * K + ka1 * 8;
  const int ob0 = (bn * 256 + ra0) * K + ka0 * 8;
  const int ob1 = (bn * 256 + ra1) * K + ka1 * 8;

#define STAGE(buf, kk)                                          \
  do {                                                          \
    unsigned short* Lb = lds[buf];                              \
    gl16(Ahi + oa0 + (kk), Lb + (tid) * 8);                     \
    gl16(Ahi + oa1 + (kk), Lb + (tid + 512) * 8);               \
    gl16(Alo + oa0 + (kk), Lb + (tid + 1024) * 8);              \
    gl16(Alo + oa1 + (kk), Lb + (tid + 1536) * 8);              \
    gl16(Bhi + ob0 + (kk), Lb + (tid + 2048) * 8);              \
    gl16(Bhi + ob1 + (kk), Lb + (tid + 2560) * 8);              \
    gl16(Blo + ob0 + (kk), Lb + (tid + 3072) * 8);              \
    gl16(Blo + ob1 + (kk), Lb + (tid + 3584) * 8);              \
  } while (0)

#define COMPUTE(buf)                                                          \
  do {                                                                        \
    const unsigned short* Lb = lds[buf];                                      \
    bf16x8 bh[4], bl[4], af[8];                                               \
    _Pragma("unroll")                                                         \
    for (int nj = 0; nj < 4; ++nj) {                                          \
      int slot = lk * 256 + wn * 64 + nj * 16 + lr;                           \
      bh[nj] = *(const bf16x8*)(Lb + 16384 + slot * 8);                       \
      bl[nj] = *(const bf16x8*)(Lb + 24576 + slot * 8);                       \
    }                                                                         \
    _Pragma("unroll")                                                         \
    for (int mi = 0; mi < 8; ++mi) {                                          \
      int slot = lk * 256 + wm * 128 + mi * 16 + lr;                          \
      af[mi] = *(const bf16x8*)(Lb + slot * 8);                               \
    }                                                                         \
    _Pragma("unroll")                                                         \
    for (int mi = 0; mi < 8; ++mi)                                            \
      _Pragma("unroll")                                                       \
      for (int nj = 0; nj < 4; ++nj)                                          \
        acc[mi][nj] = __builtin_amdgcn_mfma_f32_16x16x32_bf16(af[mi], bh[nj], acc[mi][nj], 0, 0, 0); \
    _Pragma("unroll")                                                         \
    for (int mi = 0; mi < 8; ++mi)                                            \
      _Pragma("unroll")                                                       \
      for (int nj = 0; nj < 4; ++nj)                                          \
        acc[mi][nj] = __builtin_amdgcn_mfma_f32_16x16x32_bf16(af[mi], bl[nj], acc[mi][nj], 0, 0, 0); \
    _Pragma("unroll")                                                         \
    for (int mi = 0; mi < 8; ++mi) {                                          \
      int slot = lk * 256 + wm * 128 + mi * 16 + lr;                          \
      af[mi] = *(const bf16x8*)(Lb + 8192 + slot * 8);                        \
    }                                                                         \
    _Pragma("unroll")                                                         \
    for (int mi = 0; mi < 8; ++mi)                                            \
      _Pragma("unroll")                                                       \
      for (int nj = 0; nj < 4; ++nj)                                          \
        acc[mi][nj] = __builtin_amdgcn_mfma_f32_16x16x32_bf16(af[mi], bh[nj], acc[mi][nj], 0, 0, 0); \
  } while (0)

  const int nt = K >> 5;                       // 16 K-steps
  STAGE(0, 0);
  STAGE(1, 32);

  for (int t = 0; t < nt - 1; ++t) {
    asm volatile("s_waitcnt vmcnt(8)" ::: "memory");
    __builtin_amdgcn_sched_barrier(0);
    __builtin_amdgcn_s_barrier();
    COMPUTE(t & 1);
    __builtin_amdgcn_s_barrier();
    if (t < nt - 2) STAGE(t & 1, (t + 2) << 5);
  }
  asm volatile("s_waitcnt vmcnt(0)" ::: "memory");
  __builtin_amdgcn_sched_barrier(0);
  __builtin_amdgcn_s_barrier();
  COMPUTE((nt - 1) & 1);

#pragma unroll
  for (int nj = 0; nj < 4; ++nj) {
    int gn = bn * 256 + wn * 64 + nj * 16 + lr;
    float bv = bias[gn];
    float s = 0.f, qq = 0.f;
#pragma unroll
    for (int mi = 0; mi < 8; ++mi) {
      int gm = bm * 256 + wm * 128 + mi * 16 + (lk << 2);
#pragma unroll
      for (int r = 0; r < 4; ++r) {
        float v = acc[mi][nj][r] + bv;
        C[(gm + r) * C_DIM + gn] = v;
        s += v; qq += v * v;
      }
    }
    s  += __shfl_xor(s, 16);  qq += __shfl_xor(qq, 16);
    s  += __shfl_xor(s, 32);  qq += __shfl_xor(qq, 32);
    if (lk == 0) {
      atomicAdd(&gsum[gn], s);
      atomicAdd(&gsq[gn], qq);
    }
  }
#undef STAGE
#undef COMPUTE
}

// ---------------- parallel-scan IndRNN (register-cached) ----------------
// h_t = max(x_t + u h_{t-1}, 0). Maps h -> max(A + B h, M) form a monoid (B >= 0):
//   (A2,B2,M2) o (A1,B1,M1) = (A2 + B2*A1, B2*B1, max(A2 + B2*M1, M2))
// Block = 1024 threads = 16 waves; wave w owns L-rows [64w,64w+64) of 64 chains (lanes).
// Phase1: load segment into v[64] REGISTERS + triple. Phase2: LDS prefix compose.
// Phase3: exact replay from registers (no re-read). ~100 VGPR -> 4 waves/SIMD kept.

// BN(finalize inline) + IndRNN, emit h as bf16 hi/lo for GEMM2
__global__ __launch_bounds__(1024, 4)
void k_indrnn_split(const float* __restrict__ y,
                    const float* __restrict__ gsum, const float* __restrict__ gsq,
                    const float* __restrict__ g, const float* __restrict__ be,
                    const float* __restrict__ u,
                    unsigned short* __restrict__ hhi, unsigned short* __restrict__ hlo) {
  __shared__ float tA[1024], tB[1024], tM[1024];
  int lane = threadIdx.x & 63;
  int w = threadIdx.x >> 6;                 // segment 0..15
  int chain = blockIdx.x * 64 + lane;       // (n,c) flat index
  int c = chain & 511;
  float m  = gsum[c] * (1.0f / (float)M_DIM);
  float vv = gsq[c]  * (1.0f / (float)M_DIM) - m * m;
  float sc = g[c] * rsqrtf(vv + EPS_BN);
  float sh = be[c] - m * sc;
  float uu = u[c];
  const float* py = y + chain;
  const int base = w * 64;

  // phase 1: load entire segment to registers, compute triple
  float v[64];
#pragma unroll
  for (int i = 0; i < 64; ++i) v[i] = py[(base + i) * 16384];
  float A = 0.f, Bc = 1.f, Mx = 0.f;
#pragma unroll
  for (int i = 0; i < 64; ++i) {
    float xt = fmaf(v[i], sc, sh);
    A  = fmaf(uu, A, xt);
    Mx = fmaxf(fmaf(uu, Mx, xt), 0.f);
    Bc *= uu;
  }
  tA[w * 64 + lane] = A; tB[w * 64 + lane] = Bc; tM[w * 64 + lane] = Mx;
  __syncthreads();

  // phase 2: prefix compose segments 0..w-1
  float pA = 0.f, pM = 0.f;
  for (int s = 0; s < w; ++s) {
    float a = tA[s * 64 + lane], b = tB[s * 64 + lane], mm = tM[s * 64 + lane];
    pA = fmaf(b, pA, a);
    pM = fmaxf(fmaf(b, pM, a), mm);
  }
  float h = fmaxf(pA, pM);        // h_start for this segment (h0 = 0)

  // phase 3: exact replay from registers, emit bf16 hi/lo
  unsigned short* ph = hhi + chain;
  unsigned short* pl = hlo + chain;
#pragma unroll
  for (int i = 0; i < 64; ++i) {
    float xt = fmaf(v[i], sc, sh);
    h = fmaxf(fmaf(uu, h, xt), 0.f);
    unsigned short hb = f2bf(h);
    int off = (base + i) * 16384;
    ph[off] = hb;
    pl[off] = f2bf(h - bf2f(hb));
  }
}

// BN(finalize inline) + IndRNN + residual, in place on d_out (y cached, x streamed)
__global__ __launch_bounds__(1024, 4)
void k_indrnn_res(float* __restrict__ y, const float* __restrict__ x,
                  const float* __restrict__ gsum, const float* __restrict__ gsq,
                  const float* __restrict__ g, const float* __restrict__ be,
                  const float* __restrict__ u) {
  __shared__ float tA[1024], tB[1024], tM[1024];
  int lane = threadIdx.x & 63;
  int w = threadIdx.x >> 6;
  int chain = blockIdx.x * 64 + lane;
  int c = chain & 511;
  float m  = gsum[c] * (1.0f / (float)M_DIM);
  float vv = gsq[c]  * (1.0f / (float)M_DIM) - m * m;
  float sc = g[c] * rsqrtf(vv + EPS_BN);
  float sh = be[c] - m * sc;
  float uu = u[c];
  float* py = y + chain;
  const float* px = x + chain;
  const int base = w * 64;

  float v[64];
#pragma unroll
  for (int i = 0; i < 64; ++i) v[i] = py[(base + i) * 16384];
  float A = 0.f, Bc = 1.f, Mx = 0.f;
#pragma unroll
  for (int i = 0; i < 64; ++i) {
    float xt = fmaf(v[i], sc, sh);
    A  = fmaf(uu, A, xt);
    Mx = fmaxf(fmaf(uu, Mx, xt), 0.f);
    Bc *= uu;
  }
  tA[w * 64 + lane] = A; tB[w * 64 + lane] = Bc; tM[w * 64 + lane] = Mx;
  __syncthreads();

  float pA = 0.f, pM = 0.f;
  for (int s = 0; s < w; ++s) {
    float a = tA[s * 64 + lane], b = tB[s * 64 + lane], mm = tM[s * 64 + lane];
    pA = fmaf(b, pA, a);
    pM = fmaxf(fmaf(b, pM, a), mm);
  }
  float h = fmaxf(pA, pM);

  // phase 3: replay from registers; stream x in 16-chunks
#pragma unroll
  for (int c0 = 0; c0 < 64; c0 += 16) {
    float xb[16];
#pragma unroll
    for (int i = 0; i < 16; ++i) xb[i] = px[(base + c0 + i) * 16384];
#pragma unroll
    for (int i = 0; i < 16; ++i) {
      float xt = fmaf(v[c0 + i], sc, sh);
      h = fmaxf(fmaf(uu, h, xt), 0.f);
      py[(base + c0 + i) * 16384] = h + xb[i];
    }
  }
}

extern "C" void kernel_launch(void* const* d_in, const int* in_sizes, int n_in,
                              void* d_out, int out_size, void* d_ws, size_t ws_size,
                              hipStream_t stream) {
  if (n_in < 11) return;
  const float* x   = (const float*)d_in[0];
  const float* W1  = (const float*)d_in[1];
  const float* b1  = (const float*)d_in[2];
  const float* g1  = (const float*)d_in[3];
  const float* be1 = (const float*)d_in[4];
  const float* u1  = (const float*)d_in[5];
  const float* W2  = (const float*)d_in[6];
  const float* b2  = (const float*)d_in[7];
  const float* g2  = (const float*)d_in[8];
  const float* be2 = (const float*)d_in[9];
  const float* u2  = (const float*)d_in[10];
  float* out = (float*)d_out;

  char* ws = (char*)d_ws;
  const size_t SZ_HALF = (size_t)M_DIM * C_DIM * sizeof(unsigned short);
  const size_t SZ_W    = (size_t)C_DIM * C_DIM * sizeof(unsigned short);
  unsigned short* Ahi  = (unsigned short*)(ws);             // x split; reused as h1 split
  unsigned short* Alo  = (unsigned short*)(ws + SZ_HALF);
  unsigned short* W1hi = (unsigned short*)(ws + 2 * SZ_HALF);
  unsigned short* W1lo = W1hi + C_DIM * C_DIM;
  unsigned short* W2hi = W1lo + C_DIM * C_DIM;
  unsigned short* W2lo = W2hi + C_DIM * C_DIM;
  float* stats = (float*)(ws + 2 * SZ_HALF + 4 * SZ_W);
  float* sum1 = stats,        *sq1 = stats + 512;
  float* sum2 = stats + 1024, *sq2 = stats + 1536;
  if (ws_size < 2 * SZ_HALF + 4 * SZ_W + 4 * 512 * sizeof(float)) return;

  hipMemsetAsync(stats, 0, 4 * 512 * sizeof(float), stream);

  k_split_all<<<2048, 256, 0, stream>>>(x, W1, W2, Ahi, Alo, W1hi, W1lo, W2hi, W2lo);

  dim3 gemmGrid(256);
  k_gemm<<<gemmGrid, 512, 0, stream>>>(Ahi, Alo, W1hi, W1lo, b1, out, sum1, sq1);
  k_indrnn_split<<<256, 1024, 0, stream>>>(out, sum1, sq1, g1, be1, u1, Ahi, Alo);

  k_gemm<<<gemmGrid, 512, 0, stream>>>(Ahi, Alo, W2hi, W2lo, b2, out, sum2, sq2);
  k_indrnn_res<<<256, 1024, 0, stream>>>(out, x, sum2, sq2, g2, be2, u2);
}

// Round 9
// 192.537 us; speedup vs baseline: 1.5354x; 1.5354x over previous
//
#include <hip/hip_runtime.h>
#include <stdint.h>

#define L_DIM 1024
#define N_DIM 32
#define C_DIM 512
#define M_DIM (L_DIM * N_DIM)   // 32768 rows for the GEMMs
#define EPS_BN 1e-5f

typedef __attribute__((ext_vector_type(8))) short bf16x8;
typedef __attribute__((ext_vector_type(4))) float f32x4;

__device__ __forceinline__ unsigned short f2bf(float f) {
  union { float f; unsigned int u; } a; a.f = f;
  unsigned int u = a.u;
  return (unsigned short)((u + 0x7FFFu + ((u >> 16) & 1u)) >> 16); // RNE
}
__device__ __forceinline__ float bf2f(unsigned short h) {
  union { float f; unsigned int u; } a; a.u = ((unsigned int)h) << 16;
  return a.f;
}

__device__ __forceinline__ void gl16(const void* g, void* l) {
  __builtin_amdgcn_global_load_lds(
      (const __attribute__((address_space(1))) unsigned int*)g,
      (__attribute__((address_space(3))) unsigned int*)l, 16, 0, 0);
}

// ---------------- split: x -> bf16 hi only; W1,W2 -> bf16 hi/lo ----------------
__global__ void k_split_all(const float* __restrict__ x, const float* __restrict__ W1,
                            const float* __restrict__ W2,
                            unsigned short* __restrict__ Ahi,
                            unsigned short* __restrict__ W1hi, unsigned short* __restrict__ W1lo,
                            unsigned short* __restrict__ W2hi, unsigned short* __restrict__ W2lo) {
  const int NX = M_DIM * C_DIM / 4;      // 4,194,304 float4
  const int NW = C_DIM * C_DIM / 4;      // 65,536 float4
  int i = blockIdx.x * 256 + threadIdx.x;
  int stride = gridDim.x * 256;
  for (; i < NX + 2 * NW; i += stride) {
    if (i < NX) {
      float4 v = ((const float4*)x)[i];
      ushort4 h;
      h.x = f2bf(v.x); h.y = f2bf(v.y); h.z = f2bf(v.z); h.w = f2bf(v.w);
      ((ushort4*)Ahi)[i] = h;
    } else {
      const float4* src; unsigned short* dh; unsigned short* dl; int j;
      if (i < NX + NW) { src = (const float4*)W1; dh = W1hi; dl = W1lo; j = i - NX; }
      else             { src = (const float4*)W2; dh = W2hi; dl = W2lo; j = i - NX - NW; }
      float4 v = src[j];
      ushort4 h, l;
      h.x = f2bf(v.x); l.x = f2bf(v.x - bf2f(h.x));
      h.y = f2bf(v.y); l.y = f2bf(v.y - bf2f(h.y));
      h.z = f2bf(v.z); l.z = f2bf(v.z - bf2f(h.z));
      h.w = f2bf(v.w); l.w = f2bf(v.w - bf2f(h.w));
      ((ushort4*)dh)[j] = h;
      ((ushort4*)dl)[j] = l;
    }
  }
}

// ---------------- bf16x2 MFMA GEMM: C = A(hi) * (Bhi+Blo)^T + bias, fused BN stats ----------------
// A: (M x K) bf16 hi only (A-side lo dropped: incoherent quantization error).
// B: (N x K) bf16 hi/lo (weights: lo kept — its error is coherent across rows).
// R5 sync structure (best validated): 256x256 tile, BK=32, 512 threads = 8 waves (2M x 4N),
// wave-tile 128x64, monolithic 2-pass COMPUTE, 2 barriers + counted vmcnt(6) per K-step,
// double-buffered 96KB LDS, grid 256 = 1 block/CU, XCD swizzle.
__global__ __launch_bounds__(512, 2)
void k_gemm(const unsigned short* __restrict__ Ahi,
            const unsigned short* __restrict__ Bhi, const unsigned short* __restrict__ Blo,
            const float* __restrict__ bias, float* __restrict__ C,
            float* __restrict__ gsum, float* __restrict__ gsq) {
  const int K = C_DIM;
  int d = blockIdx.x;
  int xcd = d & 7;
  int q = d >> 3;                  // 0..31
  int bm = xcd * 16 + (q >> 1);    // 0..127
  int bn = q & 1;                  // 0..1

  // per buffer 48KB = 3072 slots of 16B: A [0,1024), Bhi [1024,2048), Blo [2048,3072)
  // slot within matrix: m = kc*256 + row (kc = k-chunk of 8 elems)
  __shared__ unsigned short lds[2][24576];   // 96 KB total

  int tid  = threadIdx.x;
  int lane = tid & 63;
  int wave = tid >> 6;
  int wm = wave >> 2;              // 0..1
  int wn = wave & 3;               // 0..3
  int lr = lane & 15;
  int lk = lane >> 4;

  f32x4 acc[8][4];
#pragma unroll
  for (int i = 0; i < 8; ++i)
#pragma unroll
    for (int j = 0; j < 4; ++j) acc[i][j] = (f32x4){0.f, 0.f, 0.f, 0.f};

  const int ra0 = tid & 255, ka0 = (tid >> 8) & 3;
  const int ra1 = (tid + 512) & 255, ka1 = ((tid + 512) >> 8) & 3;
  const int oa0 = (bm * 256 + ra0) * K + ka0 * 8;
  const int oa1 = (bm * 256 + ra1) * K + ka1 * 8;
  const int ob0 = (bn * 256 + ra0) * K + ka0 * 8;
  const int ob1 = (bn * 256 + ra1) * K + ka1 * 8;

#define STAGE(buf, kk)                                          \
  do {                                                          \
    unsigned short* Lb = lds[buf];                              \
    gl16(Ahi + oa0 + (kk), Lb + (tid) * 8);                     \
    gl16(Ahi + oa1 + (kk), Lb + (tid + 512) * 8);               \
    gl16(Bhi + ob0 + (kk), Lb + (tid + 1024) * 8);              \
    gl16(Bhi + ob1 + (kk), Lb + (tid + 1536) * 8);              \
    gl16(Blo + ob0 + (kk), Lb + (tid + 2048) * 8);              \
    gl16(Blo + ob1 + (kk), Lb + (tid + 2560) * 8);              \
  } while (0)

#define COMPUTE(buf)                                                          \
  do {                                                                        \
    const unsigned short* Lb = lds[buf];                                      \
    bf16x8 bh[4], bl[4], af[8];                                               \
    _Pragma("unroll")                                                         \
    for (int nj = 0; nj < 4; ++nj) {                                          \
      int slot = lk * 256 + wn * 64 + nj * 16 + lr;                           \
      bh[nj] = *(const bf16x8*)(Lb + 8192 + slot * 8);                        \
      bl[nj] = *(const bf16x8*)(Lb + 16384 + slot * 8);                       \
    }                                                                         \
    _Pragma("unroll")                                                         \
    for (int mi = 0; mi < 8; ++mi) {                                          \
      int slot = lk * 256 + wm * 128 + mi * 16 + lr;                          \
      af[mi] = *(const bf16x8*)(Lb + slot * 8);                               \
    }                                                                         \
    _Pragma("unroll")                                                         \
    for (int mi = 0; mi < 8; ++mi)                                            \
      _Pragma("unroll")                                                       \
      for (int nj = 0; nj < 4; ++nj)                                          \
        acc[mi][nj] = __builtin_amdgcn_mfma_f32_16x16x32_bf16(af[mi], bh[nj], acc[mi][nj], 0, 0, 0); \
    _Pragma("unroll")                                                         \
    for (int mi = 0; mi < 8; ++mi)                                            \
      _Pragma("unroll")                                                       \
      for (int nj = 0; nj < 4; ++nj)                                          \
        acc[mi][nj] = __builtin_amdgcn_mfma_f32_16x16x32_bf16(af[mi], bl[nj], acc[mi][nj], 0, 0, 0); \
  } while (0)

  const int nt = K >> 5;                       // 16 K-steps
  STAGE(0, 0);
  STAGE(1, 32);                                // 12 loads/thread outstanding

  for (int t = 0; t < nt - 1; ++t) {
    asm volatile("s_waitcnt vmcnt(6)" ::: "memory");  // tile t landed; t+1's 6 in flight
    __builtin_amdgcn_sched_barrier(0);
    __builtin_amdgcn_s_barrier();
    COMPUTE(t & 1);
    __builtin_amdgcn_s_barrier();
    if (t < nt - 2) STAGE(t & 1, (t + 2) << 5);
  }
  asm volatile("s_waitcnt vmcnt(0)" ::: "memory");
  __builtin_amdgcn_sched_barrier(0);
  __builtin_amdgcn_s_barrier();
  COMPUTE((nt - 1) & 1);

  // epilogue: C/D layout col = lane&15, row = (lane>>4)*4 + r; fused bias + BN partial stats
#pragma unroll
  for (int nj = 0; nj < 4; ++nj) {
    int gn = bn * 256 + wn * 64 + nj * 16 + lr;
    float bv = bias[gn];
    float s = 0.f, qq = 0.f;
#pragma unroll
    for (int mi = 0; mi < 8; ++mi) {
      int gm = bm * 256 + wm * 128 + mi * 16 + (lk << 2);
#pragma unroll
      for (int r = 0; r < 4; ++r) {
        float v = acc[mi][nj][r] + bv;
        C[(gm + r) * C_DIM + gn] = v;
        s += v; qq += v * v;
      }
    }
    s  += __shfl_xor(s, 16);  qq += __shfl_xor(qq, 16);
    s  += __shfl_xor(s, 32);  qq += __shfl_xor(qq, 32);
    if (lk == 0) {
      atomicAdd(&gsum[gn], s);
      atomicAdd(&gsq[gn], qq);
    }
  }
#undef STAGE
#undef COMPUTE
}

// ---------------- parallel-scan IndRNN (R5 structure) ----------------
// h_t = max(x_t + u h_{t-1}, 0). Maps h -> max(A + B h, M) form a monoid (B >= 0):
//   (A2,B2,M2) o (A1,B1,M1) = (A2 + B2*A1, B2*B1, max(A2 + B2*M1, M2))
// Block = 1024 threads = 16 waves; wave w owns L-rows [64w,64w+64) of 64 chains (lanes).
// Phase1: segment triple. Phase2: LDS prefix compose. Phase3: exact replay.

// BN(finalize inline) + IndRNN, emit h as bf16 hi (GEMM2's A is hi-only)
__global__ __launch_bounds__(1024, 4)
void k_indrnn_split(const float* __restrict__ y,
                    const float* __restrict__ gsum, const float* __restrict__ gsq,
                    const float* __restrict__ g, const float* __restrict__ be,
                    const float* __restrict__ u,
                    unsigned short* __restrict__ hhi) {
  __shared__ float tA[1024], tB[1024], tM[1024];
  int lane = threadIdx.x & 63;
  int w = threadIdx.x >> 6;                 // segment 0..15
  int chain = blockIdx.x * 64 + lane;       // (n,c) flat index
  int c = chain & 511;
  float m  = gsum[c] * (1.0f / (float)M_DIM);
  float vv = gsq[c]  * (1.0f / (float)M_DIM) - m * m;
  float sc = g[c] * rsqrtf(vv + EPS_BN);
  float sh = be[c] - m * sc;
  float uu = u[c];
  const float* py = y + chain;
  const int base = w * 64;

  float A = 0.f, Bc = 1.f, Mx = 0.f;
  for (int c0 = 0; c0 < 64; c0 += 16) {
    float vb[16];
#pragma unroll
    for (int i = 0; i < 16; ++i) vb[i] = py[(base + c0 + i) * 16384];
#pragma unroll
    for (int i = 0; i < 16; ++i) {
      float xt = fmaf(vb[i], sc, sh);
      A  = fmaf(uu, A, xt);
      Mx = fmaxf(fmaf(uu, Mx, xt), 0.f);
      Bc *= uu;
    }
  }
  tA[w * 64 + lane] = A; tB[w * 64 + lane] = Bc; tM[w * 64 + lane] = Mx;
  __syncthreads();

  float pA = 0.f, pM = 0.f;
  for (int s = 0; s < w; ++s) {
    float a = tA[s * 64 + lane], b = tB[s * 64 + lane], mm = tM[s * 64 + lane];
    pA = fmaf(b, pA, a);
    pM = fmaxf(fmaf(b, pM, a), mm);
  }
  float h = fmaxf(pA, pM);        // h_start for this segment (h0 = 0)

  unsigned short* ph = hhi + chain;
  for (int c0 = 0; c0 < 64; c0 += 16) {
    float vb[16];
#pragma unroll
    for (int i = 0; i < 16; ++i) vb[i] = py[(base + c0 + i) * 16384];
#pragma unroll
    for (int i = 0; i < 16; ++i) {
      float xt = fmaf(vb[i], sc, sh);
      h = fmaxf(fmaf(uu, h, xt), 0.f);
      ph[(base + c0 + i) * 16384] = f2bf(h);
    }
  }
}

// BN(finalize inline) + IndRNN + residual, in place on d_out
__global__ __launch_bounds__(1024, 4)
void k_indrnn_res(float* __restrict__ y, const float* __restrict__ x,
                  const float* __restrict__ gsum, const float* __restrict__ gsq,
                  const float* __restrict__ g, const float* __restrict__ be,
                  const float* __restrict__ u) {
  __shared__ float tA[1024], tB[1024], tM[1024];
  int lane = threadIdx.x & 63;
  int w = threadIdx.x >> 6;
  int chain = blockIdx.x * 64 + lane;
  int c = chain & 511;
  float m  = gsum[c] * (1.0f / (float)M_DIM);
  float vv = gsq[c]  * (1.0f / (float)M_DIM) - m * m;
  float sc = g[c] * rsqrtf(vv + EPS_BN);
  float sh = be[c] - m * sc;
  float uu = u[c];
  float* py = y + chain;
  const float* px = x + chain;
  const int base = w * 64;

  float A = 0.f, Bc = 1.f, Mx = 0.f;
  for (int c0 = 0; c0 < 64; c0 += 16) {
    float vb[16];
#pragma unroll
    for (int i = 0; i < 16; ++i) vb[i] = py[(base + c0 + i) * 16384];
#pragma unroll
    for (int i = 0; i < 16; ++i) {
      float xt = fmaf(vb[i], sc, sh);
      A  = fmaf(uu, A, xt);
      Mx = fmaxf(fmaf(uu, Mx, xt), 0.f);
      Bc *= uu;
    }
  }
  tA[w * 64 + lane] = A; tB[w * 64 + lane] = Bc; tM[w * 64 + lane] = Mx;
  __syncthreads();

  float pA = 0.f, pM = 0.f;
  for (int s = 0; s < w; ++s) {
    float a = tA[s * 64 + lane], b = tB[s * 64 + lane], mm = tM[s * 64 + lane];
    pA = fmaf(b, pA, a);
    pM = fmaxf(fmaf(b, pM, a), mm);
  }
  float h = fmaxf(pA, pM);

  for (int c0 = 0; c0 < 64; c0 += 16) {
    float vb[16], xb[16];
#pragma unroll
    for (int i = 0; i < 16; ++i) vb[i] = py[(base + c0 + i) * 16384];
#pragma unroll
    for (int i = 0; i < 16; ++i) xb[i] = px[(base + c0 + i) * 16384];
#pragma unroll
    for (int i = 0; i < 16; ++i) {
      float xt = fmaf(vb[i], sc, sh);
      h = fmaxf(fmaf(uu, h, xt), 0.f);
      py[(base + c0 + i) * 16384] = h + xb[i];
    }
  }
}

extern "C" void kernel_launch(void* const* d_in, const int* in_sizes, int n_in,
                              void* d_out, int out_size, void* d_ws, size_t ws_size,
                              hipStream_t stream) {
  if (n_in < 11) return;
  const float* x   = (const float*)d_in[0];
  const float* W1  = (const float*)d_in[1];
  const float* b1  = (const float*)d_in[2];
  const float* g1  = (const float*)d_in[3];
  const float* be1 = (const float*)d_in[4];
  const float* u1  = (const float*)d_in[5];
  const float* W2  = (const float*)d_in[6];
  const float* b2  = (const float*)d_in[7];
  const float* g2  = (const float*)d_in[8];
  const float* be2 = (const float*)d_in[9];
  const float* u2  = (const float*)d_in[10];
  float* out = (float*)d_out;

  char* ws = (char*)d_ws;
  const size_t SZ_HALF = (size_t)M_DIM * C_DIM * sizeof(unsigned short); // 33,554,432 B
  const size_t SZ_W    = (size_t)C_DIM * C_DIM * sizeof(unsigned short); //    524,288 B
  unsigned short* Ahi  = (unsigned short*)(ws);             // x hi; reused as h1 hi
  unsigned short* W1hi = (unsigned short*)(ws + SZ_HALF);
  unsigned short* W1lo = W1hi + C_DIM * C_DIM;
  unsigned short* W2hi = W1lo + C_DIM * C_DIM;
  unsigned short* W2lo = W2hi + C_DIM * C_DIM;
  float* stats = (float*)(ws + SZ_HALF + 4 * SZ_W);
  float* sum1 = stats,        *sq1 = stats + 512;
  float* sum2 = stats + 1024, *sq2 = stats + 1536;
  if (ws_size < SZ_HALF + 4 * SZ_W + 4 * 512 * sizeof(float)) return;

  hipMemsetAsync(stats, 0, 4 * 512 * sizeof(float), stream);

  k_split_all<<<2048, 256, 0, stream>>>(x, W1, W2, Ahi, W1hi, W1lo, W2hi, W2lo);

  dim3 gemmGrid(256);   // 1 block/CU
  k_gemm<<<gemmGrid, 512, 0, stream>>>(Ahi, W1hi, W1lo, b1, out, sum1, sq1);
  k_indrnn_split<<<256, 1024, 0, stream>>>(out, sum1, sq1, g1, be1, u1, Ahi);

  k_gemm<<<gemmGrid, 512, 0, stream>>>(Ahi, W2hi, W2lo, b2, out, sum2, sq2);
  k_indrnn_res<<<256, 1024, 0, stream>>>(out, x, sum2, sq2, g2, be2, u2);
}

// Round 10
// 168.997 us; speedup vs baseline: 1.7492x; 1.1393x over previous
//
#include <hip/hip_runtime.h>
#include <stdint.h>

#define L_DIM 1024
#define N_DIM 32
#define C_DIM 512
#define M_DIM (L_DIM * N_DIM)   // 32768 rows for the GEMMs
#define EPS_BN 1e-5f

typedef __attribute__((ext_vector_type(8))) short bf16x8;
typedef __attribute__((ext_vector_type(4))) float f32x4;

__device__ __forceinline__ unsigned short f2bf(float f) {
  union { float f; unsigned int u; } a; a.f = f;
  unsigned int u = a.u;
  return (unsigned short)((u + 0x7FFFu + ((u >> 16) & 1u)) >> 16); // RNE
}
__device__ __forceinline__ float bf2f(unsigned short h) {
  union { float f; unsigned int u; } a; a.u = ((unsigned int)h) << 16;
  return a.f;
}

__device__ __forceinline__ void gl16(const void* g, void* l) {
  __builtin_amdgcn_global_load_lds(
      (const __attribute__((address_space(1))) unsigned int*)g,
      (__attribute__((address_space(3))) unsigned int*)l, 16, 0, 0);
}

// ---------------- cast fp32 -> bf16 (RNE): x, W1, W2 ----------------
__global__ void k_split_all(const float* __restrict__ x, const float* __restrict__ W1,
                            const float* __restrict__ W2,
                            unsigned short* __restrict__ Ahi,
                            unsigned short* __restrict__ W1hi,
                            unsigned short* __restrict__ W2hi) {
  const int NX = M_DIM * C_DIM / 4;      // 4,194,304 float4
  const int NW = C_DIM * C_DIM / 4;      // 65,536 float4
  int i = blockIdx.x * 256 + threadIdx.x;
  int stride = gridDim.x * 256;
  for (; i < NX + 2 * NW; i += stride) {
    const float4* src; unsigned short* dh; int j;
    if (i < NX)            { src = (const float4*)x;  dh = Ahi;  j = i; }
    else if (i < NX + NW)  { src = (const float4*)W1; dh = W1hi; j = i - NX; }
    else                   { src = (const float4*)W2; dh = W2hi; j = i - NX - NW; }
    float4 v = src[j];
    ushort4 h;
    h.x = f2bf(v.x); h.y = f2bf(v.y); h.z = f2bf(v.z); h.w = f2bf(v.w);
    ((ushort4*)dh)[j] = h;
  }
}

// ---------------- pure-bf16 MFMA GEMM: C = A * B^T + bias, fused BN stats ----------------
// A: (M x K) bf16. B: (N x K) bf16 (= W layout). C: (M x N) fp32.
// Error analysis (R10): W-quant error is zero-mean in t (x_t varies, BN removes mean),
// so IndRNN amplifies only by sqrt(1/(1-u^2))~16 -> output error ~0.05 << 2.0 bf16-ulp floor.
// R5 sync structure (best validated): 256x256 tile, BK=32, 512 threads = 8 waves (2M x 4N),
// wave-tile 128x64, monolithic COMPUTE, 2 barriers + counted vmcnt(4) per K-step,
// double-buffered 64KB LDS, grid 256 = 1 block/CU, XCD swizzle.
__global__ __launch_bounds__(512, 2)
void k_gemm(const unsigned short* __restrict__ Ahi,
            const unsigned short* __restrict__ Bhi,
            const float* __restrict__ bias, float* __restrict__ C,
            float* __restrict__ gsum, float* __restrict__ gsq) {
  const int K = C_DIM;
  int d = blockIdx.x;
  int xcd = d & 7;
  int q = d >> 3;                  // 0..31
  int bm = xcd * 16 + (q >> 1);    // 0..127
  int bn = q & 1;                  // 0..1

  // per buffer 32KB = 2048 slots of 16B: A [0,1024), B [1024,2048)
  // slot within matrix: m = kc*256 + row (kc = k-chunk of 8 elems)
  __shared__ unsigned short lds[2][16384];   // 64 KB total

  int tid  = threadIdx.x;
  int lane = tid & 63;
  int wave = tid >> 6;
  int wm = wave >> 2;              // 0..1
  int wn = wave & 3;               // 0..3
  int lr = lane & 15;
  int lk = lane >> 4;

  f32x4 acc[8][4];
#pragma unroll
  for (int i = 0; i < 8; ++i)
#pragma unroll
    for (int j = 0; j < 4; ++j) acc[i][j] = (f32x4){0.f, 0.f, 0.f, 0.f};

  const int ra0 = tid & 255, ka0 = (tid >> 8) & 3;
  const int ra1 = (tid + 512) & 255, ka1 = ((tid + 512) >> 8) & 3;
  const int oa0 = (bm * 256 + ra0) * K + ka0 * 8;
  const int oa1 = (bm * 256 + ra1) * K + ka1 * 8;
  const int ob0 = (bn * 256 + ra0) * K + ka0 * 8;
  const int ob1 = (bn * 256 + ra1) * K + ka1 * 8;

#define STAGE(buf, kk)                                          \
  do {                                                          \
    unsigned short* Lb = lds[buf];                              \
    gl16(Ahi + oa0 + (kk), Lb + (tid) * 8);                     \
    gl16(Ahi + oa1 + (kk), Lb + (tid + 512) * 8);               \
    gl16(Bhi + ob0 + (kk), Lb + (tid + 1024) * 8);              \
    gl16(Bhi + ob1 + (kk), Lb + (tid + 1536) * 8);              \
  } while (0)

#define COMPUTE(buf)                                                          \
  do {                                                                        \
    const unsigned short* Lb = lds[buf];                                      \
    bf16x8 bh[4], af[8];                                                      \
    _Pragma("unroll")                                                         \
    for (int nj = 0; nj < 4; ++nj) {                                          \
      int slot = lk * 256 + wn * 64 + nj * 16 + lr;                           \
      bh[nj] = *(const bf16x8*)(Lb + 8192 + slot * 8);                        \
    }                                                                         \
    _Pragma("unroll")                                                         \
    for (int mi = 0; mi < 8; ++mi) {                                          \
      int slot = lk * 256 + wm * 128 + mi * 16 + lr;                          \
      af[mi] = *(const bf16x8*)(Lb + slot * 8);                               \
    }                                                                         \
    _Pragma("unroll")                                                         \
    for (int mi = 0; mi < 8; ++mi)                                            \
      _Pragma("unroll")                                                       \
      for (int nj = 0; nj < 4; ++nj)                                          \
        acc[mi][nj] = __builtin_amdgcn_mfma_f32_16x16x32_bf16(af[mi], bh[nj], acc[mi][nj], 0, 0, 0); \
  } while (0)

  const int nt = K >> 5;                       // 16 K-steps
  STAGE(0, 0);
  STAGE(1, 32);                                // 8 loads/thread outstanding

  for (int t = 0; t < nt - 1; ++t) {
    asm volatile("s_waitcnt vmcnt(4)" ::: "memory");  // tile t landed; t+1's 4 in flight
    __builtin_amdgcn_sched_barrier(0);
    __builtin_amdgcn_s_barrier();
    COMPUTE(t & 1);
    __builtin_amdgcn_s_barrier();
    if (t < nt - 2) STAGE(t & 1, (t + 2) << 5);
  }
  asm volatile("s_waitcnt vmcnt(0)" ::: "memory");
  __builtin_amdgcn_sched_barrier(0);
  __builtin_amdgcn_s_barrier();
  COMPUTE((nt - 1) & 1);

  // epilogue: C/D layout col = lane&15, row = (lane>>4)*4 + r; fused bias + BN partial stats
#pragma unroll
  for (int nj = 0; nj < 4; ++nj) {
    int gn = bn * 256 + wn * 64 + nj * 16 + lr;
    float bv = bias[gn];
    float s = 0.f, qq = 0.f;
#pragma unroll
    for (int mi = 0; mi < 8; ++mi) {
      int gm = bm * 256 + wm * 128 + mi * 16 + (lk << 2);
#pragma unroll
      for (int r = 0; r < 4; ++r) {
        float v = acc[mi][nj][r] + bv;
        C[(gm + r) * C_DIM + gn] = v;
        s += v; qq += v * v;
      }
    }
    s  += __shfl_xor(s, 16);  qq += __shfl_xor(qq, 16);
    s  += __shfl_xor(s, 32);  qq += __shfl_xor(qq, 32);
    if (lk == 0) {
      atomicAdd(&gsum[gn], s);
      atomicAdd(&gsq[gn], qq);
    }
  }
#undef STAGE
#undef COMPUTE
}

// ---------------- parallel-scan IndRNN (R5 structure) ----------------
// h_t = max(x_t + u h_{t-1}, 0). Maps h -> max(A + B h, M) form a monoid (B >= 0):
//   (A2,B2,M2) o (A1,B1,M1) = (A2 + B2*A1, B2*B1, max(A2 + B2*M1, M2))
// Block = 1024 threads = 16 waves; wave w owns L-rows [64w,64w+64) of 64 chains (lanes).
// Phase1: segment triple. Phase2: LDS prefix compose. Phase3: exact replay.

// BN(finalize inline) + IndRNN, emit h as bf16 (GEMM2's A)
__global__ __launch_bounds__(1024, 4)
void k_indrnn_split(const float* __restrict__ y,
                    const float* __restrict__ gsum, const float* __restrict__ gsq,
                    const float* __restrict__ g, const float* __restrict__ be,
                    const float* __restrict__ u,
                    unsigned short* __restrict__ hhi) {
  __shared__ float tA[1024], tB[1024], tM[1024];
  int lane = threadIdx.x & 63;
  int w = threadIdx.x >> 6;                 // segment 0..15
  int chain = blockIdx.x * 64 + lane;       // (n,c) flat index
  int c = chain & 511;
  float m  = gsum[c] * (1.0f / (float)M_DIM);
  float vv = gsq[c]  * (1.0f / (float)M_DIM) - m * m;
  float sc = g[c] * rsqrtf(vv + EPS_BN);
  float sh = be[c] - m * sc;
  float uu = u[c];
  const float* py = y + chain;
  const int base = w * 64;

  float A = 0.f, Bc = 1.f, Mx = 0.f;
  for (int c0 = 0; c0 < 64; c0 += 16) {
    float vb[16];
#pragma unroll
    for (int i = 0; i < 16; ++i) vb[i] = py[(base + c0 + i) * 16384];
#pragma unroll
    for (int i = 0; i < 16; ++i) {
      float xt = fmaf(vb[i], sc, sh);
      A  = fmaf(uu, A, xt);
      Mx = fmaxf(fmaf(uu, Mx, xt), 0.f);
      Bc *= uu;
    }
  }
  tA[w * 64 + lane] = A; tB[w * 64 + lane] = Bc; tM[w * 64 + lane] = Mx;
  __syncthreads();

  float pA = 0.f, pM = 0.f;
  for (int s = 0; s < w; ++s) {
    float a = tA[s * 64 + lane], b = tB[s * 64 + lane], mm = tM[s * 64 + lane];
    pA = fmaf(b, pA, a);
    pM = fmaxf(fmaf(b, pM, a), mm);
  }
  float h = fmaxf(pA, pM);        // h_start for this segment (h0 = 0)

  unsigned short* ph = hhi + chain;
  for (int c0 = 0; c0 < 64; c0 += 16) {
    float vb[16];
#pragma unroll
    for (int i = 0; i < 16; ++i) vb[i] = py[(base + c0 + i) * 16384];
#pragma unroll
    for (int i = 0; i < 16; ++i) {
      float xt = fmaf(vb[i], sc, sh);
      h = fmaxf(fmaf(uu, h, xt), 0.f);
      ph[(base + c0 + i) * 16384] = f2bf(h);
    }
  }
}

// BN(finalize inline) + IndRNN + residual, in place on d_out
__global__ __launch_bounds__(1024, 4)
void k_indrnn_res(float* __restrict__ y, const float* __restrict__ x,
                  const float* __restrict__ gsum, const float* __restrict__ gsq,
                  const float* __restrict__ g, const float* __restrict__ be,
                  const float* __restrict__ u) {
  __shared__ float tA[1024], tB[1024], tM[1024];
  int lane = threadIdx.x & 63;
  int w = threadIdx.x >> 6;
  int chain = blockIdx.x * 64 + lane;
  int c = chain & 511;
  float m  = gsum[c] * (1.0f / (float)M_DIM);
  float vv = gsq[c]  * (1.0f / (float)M_DIM) - m * m;
  float sc = g[c] * rsqrtf(vv + EPS_BN);
  float sh = be[c] - m * sc;
  float uu = u[c];
  float* py = y + chain;
  const float* px = x + chain;
  const int base = w * 64;

  float A = 0.f, Bc = 1.f, Mx = 0.f;
  for (int c0 = 0; c0 < 64; c0 += 16) {
    float vb[16];
#pragma unroll
    for (int i = 0; i < 16; ++i) vb[i] = py[(base + c0 + i) * 16384];
#pragma unroll
    for (int i = 0; i < 16; ++i) {
      float xt = fmaf(vb[i], sc, sh);
      A  = fmaf(uu, A, xt);
      Mx = fmaxf(fmaf(uu, Mx, xt), 0.f);
      Bc *= uu;
    }
  }
  tA[w * 64 + lane] = A; tB[w * 64 + lane] = Bc; tM[w * 64 + lane] = Mx;
  __syncthreads();

  float pA = 0.f, pM = 0.f;
  for (int s = 0; s < w; ++s) {
    float a = tA[s * 64 + lane], b = tB[s * 64 + lane], mm = tM[s * 64 + lane];
    pA = fmaf(b, pA, a);
    pM = fmaxf(fmaf(b, pM, a), mm);
  }
  float h = fmaxf(pA, pM);

  for (int c0 = 0; c0 < 64; c0 += 16) {
    float vb[16], xb[16];
#pragma unroll
    for (int i = 0; i < 16; ++i) vb[i] = py[(base + c0 + i) * 16384];
#pragma unroll
    for (int i = 0; i < 16; ++i) xb[i] = px[(base + c0 + i) * 16384];
#pragma unroll
    for (int i = 0; i < 16; ++i) {
      float xt = fmaf(vb[i], sc, sh);
      h = fmaxf(fmaf(uu, h, xt), 0.f);
      py[(base + c0 + i) * 16384] = h + xb[i];
    }
  }
}

extern "C" void kernel_launch(void* const* d_in, const int* in_sizes, int n_in,
                              void* d_out, int out_size, void* d_ws, size_t ws_size,
                              hipStream_t stream) {
  if (n_in < 11) return;
  const float* x   = (const float*)d_in[0];
  const float* W1  = (const float*)d_in[1];
  const float* b1  = (const float*)d_in[2];
  const float* g1  = (const float*)d_in[3];
  const float* be1 = (const float*)d_in[4];
  const float* u1  = (const float*)d_in[5];
  const float* W2  = (const float*)d_in[6];
  const float* b2  = (const float*)d_in[7];
  const float* g2  = (const float*)d_in[8];
  const float* be2 = (const float*)d_in[9];
  const float* u2  = (const float*)d_in[10];
  float* out = (float*)d_out;

  char* ws = (char*)d_ws;
  const size_t SZ_HALF = (size_t)M_DIM * C_DIM * sizeof(unsigned short); // 33,554,432 B
  const size_t SZ_W    = (size_t)C_DIM * C_DIM * sizeof(unsigned short); //    524,288 B
  unsigned short* Ahi  = (unsigned short*)(ws);             // x bf16; reused as h1 bf16
  unsigned short* W1hi = (unsigned short*)(ws + SZ_HALF);
  unsigned short* W2hi = W1hi + C_DIM * C_DIM;
  float* stats = (float*)(ws + SZ_HALF + 2 * SZ_W);
  float* sum1 = stats,        *sq1 = stats + 512;
  float* sum2 = stats + 1024, *sq2 = stats + 1536;
  if (ws_size < SZ_HALF + 2 * SZ_W + 4 * 512 * sizeof(float)) return;

  hipMemsetAsync(stats, 0, 4 * 512 * sizeof(float), stream);

  k_split_all<<<2048, 256, 0, stream>>>(x, W1, W2, Ahi, W1hi, W2hi);

  dim3 gemmGrid(256);   // 1 block/CU
  k_gemm<<<gemmGrid, 512, 0, stream>>>(Ahi, W1hi, b1, out, sum1, sq1);
  k_indrnn_split<<<256, 1024, 0, stream>>>(out, sum1, sq1, g1, be1, u1, Ahi);

  k_gemm<<<gemmGrid, 512, 0, stream>>>(Ahi, W2hi, b2, out, sum2, sq2);
  k_indrnn_res<<<256, 1024, 0, stream>>>(out, x, sum2, sq2, g2, be2, u2);
}

// Round 11
// 158.450 us; speedup vs baseline: 1.8657x; 1.0666x over previous
//
#include <hip/hip_runtime.h>
#include <stdint.h>

#define L_DIM 1024
#define N_DIM 32
#define C_DIM 512
#define M_DIM (L_DIM * N_DIM)   // 32768 rows for the GEMMs
#define EPS_BN 1e-5f

typedef __attribute__((ext_vector_type(8))) short bf16x8;
typedef __attribute__((ext_vector_type(4))) float f32x4;

__device__ __forceinline__ unsigned short f2bf(float f) {
  union { float f; unsigned int u; } a; a.f = f;
  unsigned int u = a.u;
  return (unsigned short)((u + 0x7FFFu + ((u >> 16) & 1u)) >> 16); // RNE
}
__device__ __forceinline__ float bf2f(unsigned short h) {
  union { float f; unsigned int u; } a; a.u = ((unsigned int)h) << 16;
  return a.f;
}

__device__ __forceinline__ void gl16(const void* g, void* l) {
  __builtin_amdgcn_global_load_lds(
      (const __attribute__((address_space(1))) unsigned int*)g,
      (__attribute__((address_space(3))) unsigned int*)l, 16, 0, 0);
}

// ---------------- cast fp32 -> bf16 (RNE): x, W1, W2 ----------------
__global__ void k_split_all(const float* __restrict__ x, const float* __restrict__ W1,
                            const float* __restrict__ W2,
                            unsigned short* __restrict__ Ahi,
                            unsigned short* __restrict__ W1hi,
                            unsigned short* __restrict__ W2hi) {
  const int NX = M_DIM * C_DIM / 4;      // 4,194,304 float4
  const int NW = C_DIM * C_DIM / 4;      // 65,536 float4
  int i = blockIdx.x * 256 + threadIdx.x;
  int stride = gridDim.x * 256;
  for (; i < NX + 2 * NW; i += stride) {
    const float4* src; unsigned short* dh; int j;
    if (i < NX)            { src = (const float4*)x;  dh = Ahi;  j = i; }
    else if (i < NX + NW)  { src = (const float4*)W1; dh = W1hi; j = i - NX; }
    else                   { src = (const float4*)W2; dh = W2hi; j = i - NX - NW; }
    float4 v = src[j];
    ushort4 h;
    h.x = f2bf(v.x); h.y = f2bf(v.y); h.z = f2bf(v.z); h.w = f2bf(v.w);
    ((ushort4*)dh)[j] = h;
  }
}

// ---------------- pure-bf16 MFMA GEMM: C(bf16) = A * B^T + bias, fused BN stats ----------------
// A: (M x K) bf16. B: (N x K) bf16 (= W layout). C: (M x N) bf16 (stats from fp32 acc).
// 128x128 tile, BK=32, 256 threads = 4 waves (2x2), wave-tile 64x64 (4x4 frags, 16 MFMA/step).
// R5-validated sync: monolithic COMPUTE, 2 barriers + counted vmcnt(4)/K-step, dbuf 2x16KB LDS.
// Grid 1024 = 4 blocks/CU (cross-block TLP fills barrier stalls). XCD swizzle: 32 bm x 4 bn per XCD.
__global__ __launch_bounds__(256, 4)
void k_gemm(const unsigned short* __restrict__ A,
            const unsigned short* __restrict__ B,
            const float* __restrict__ bias, unsigned short* __restrict__ C,
            float* __restrict__ gsum, float* __restrict__ gsq) {
  const int K = C_DIM;
  int d = blockIdx.x;
  int xcd = d & 7;
  int q = d >> 3;                  // 0..127
  int bm = xcd * 32 + (q >> 2);    // 0..255
  int bn = q & 3;                  // 0..3

  // per buffer 16KB = 1024 slots of 16B: A [0,512), B [512,1024); slot = kc*128 + row
  __shared__ unsigned short lds[2][8192];    // 32 KB total

  int tid  = threadIdx.x;
  int lane = tid & 63;
  int wave = tid >> 6;
  int wm = wave >> 1;              // 0..1
  int wn = wave & 1;               // 0..1
  int lr = lane & 15;
  int lk = lane >> 4;

  f32x4 acc[4][4];
#pragma unroll
  for (int i = 0; i < 4; ++i)
#pragma unroll
    for (int j = 0; j < 4; ++j) acc[i][j] = (f32x4){0.f, 0.f, 0.f, 0.f};

  const int ra = tid & 127, ka = tid >> 7;       // ka 0..1; slots tid (kc=ka) and tid+256 (kc=ka+2)
  const int oa0 = (bm * 128 + ra) * K + ka * 8;
  const int oa1 = (bm * 128 + ra) * K + (ka + 2) * 8;
  const int ob0 = (bn * 128 + ra) * K + ka * 8;
  const int ob1 = (bn * 128 + ra) * K + (ka + 2) * 8;

#define STAGE(buf, kk)                                          \
  do {                                                          \
    unsigned short* Lb = lds[buf];                              \
    gl16(A + oa0 + (kk), Lb + (tid) * 8);                       \
    gl16(A + oa1 + (kk), Lb + (tid + 256) * 8);                 \
    gl16(B + ob0 + (kk), Lb + (tid + 512) * 8);                 \
    gl16(B + ob1 + (kk), Lb + (tid + 768) * 8);                 \
  } while (0)

#define COMPUTE(buf)                                                          \
  do {                                                                        \
    const unsigned short* Lb = lds[buf];                                      \
    bf16x8 bh[4], af[4];                                                      \
    _Pragma("unroll")                                                         \
    for (int nj = 0; nj < 4; ++nj) {                                          \
      int slot = 512 + lk * 128 + wn * 64 + nj * 16 + lr;                     \
      bh[nj] = *(const bf16x8*)(Lb + slot * 8);                               \
    }                                                                         \
    _Pragma("unroll")                                                         \
    for (int mi = 0; mi < 4; ++mi) {                                          \
      int slot = lk * 128 + wm * 64 + mi * 16 + lr;                           \
      af[mi] = *(const bf16x8*)(Lb + slot * 8);                               \
    }                                                                         \
    _Pragma("unroll")                                                         \
    for (int mi = 0; mi < 4; ++mi)                                            \
      _Pragma("unroll")                                                       \
      for (int nj = 0; nj < 4; ++nj)                                          \
        acc[mi][nj] = __builtin_amdgcn_mfma_f32_16x16x32_bf16(af[mi], bh[nj], acc[mi][nj], 0, 0, 0); \
  } while (0)

  const int nt = K >> 5;                       // 16 K-steps
  STAGE(0, 0);
  STAGE(1, 32);                                // 8 loads/thread outstanding

  for (int t = 0; t < nt - 1; ++t) {
    asm volatile("s_waitcnt vmcnt(4)" ::: "memory");  // tile t landed; t+1's 4 in flight
    __builtin_amdgcn_sched_barrier(0);
    __builtin_amdgcn_s_barrier();
    COMPUTE(t & 1);
    __builtin_amdgcn_s_barrier();
    if (t < nt - 2) STAGE(t & 1, (t + 2) << 5);
  }
  asm volatile("s_waitcnt vmcnt(0)" ::: "memory");
  __builtin_amdgcn_sched_barrier(0);
  __builtin_amdgcn_s_barrier();
  COMPUTE((nt - 1) & 1);

  // epilogue: C/D layout col = lane&15, row = (lane>>4)*4 + r; bf16 C + fp32 BN stats
#pragma unroll
  for (int nj = 0; nj < 4; ++nj) {
    int gn = bn * 128 + wn * 64 + nj * 16 + lr;
    float bv = bias[gn];
    float s = 0.f, qq = 0.f;
#pragma unroll
    for (int mi = 0; mi < 4; ++mi) {
      int gm = bm * 128 + wm * 64 + mi * 16 + (lk << 2);
#pragma unroll
      for (int r = 0; r < 4; ++r) {
        float v = acc[mi][nj][r] + bv;
        C[(gm + r) * C_DIM + gn] = f2bf(v);
        s += v; qq += v * v;
      }
    }
    s  += __shfl_xor(s, 16);  qq += __shfl_xor(qq, 16);
    s  += __shfl_xor(s, 32);  qq += __shfl_xor(qq, 32);
    if (lk == 0) {
      atomicAdd(&gsum[gn], s);
      atomicAdd(&gsq[gn], qq);
    }
  }
#undef STAGE
#undef COMPUTE
}

// ---------------- parallel-scan IndRNN (R5 structure, bf16 y input) ----------------
// h_t = max(x_t + u h_{t-1}, 0). Maps h -> max(A + B h, M) form a monoid (B >= 0):
//   (A2,B2,M2) o (A1,B1,M1) = (A2 + B2*A1, B2*B1, max(A2 + B2*M1, M2))
// Block = 1024 threads = 16 waves; wave w owns L-rows [64w,64w+64) of 64 chains (lanes).

// BN(finalize inline) + IndRNN, y bf16 -> h bf16 (GEMM2's A)
__global__ __launch_bounds__(1024, 4)
void k_indrnn_split(const unsigned short* __restrict__ y,
                    const float* __restrict__ gsum, const float* __restrict__ gsq,
                    const float* __restrict__ g, const float* __restrict__ be,
                    const float* __restrict__ u,
                    unsigned short* __restrict__ hhi) {
  __shared__ float tA[1024], tB[1024], tM[1024];
  int lane = threadIdx.x & 63;
  int w = threadIdx.x >> 6;                 // segment 0..15
  int chain = blockIdx.x * 64 + lane;       // (n,c) flat index
  int c = chain & 511;
  float m  = gsum[c] * (1.0f / (float)M_DIM);
  float vv = gsq[c]  * (1.0f / (float)M_DIM) - m * m;
  float sc = g[c] * rsqrtf(vv + EPS_BN);
  float sh = be[c] - m * sc;
  float uu = u[c];
  const unsigned short* py = y + chain;
  const int base = w * 64;

  float A = 0.f, Bc = 1.f, Mx = 0.f;
  for (int c0 = 0; c0 < 64; c0 += 16) {
    float vb[16];
#pragma unroll
    for (int i = 0; i < 16; ++i) vb[i] = bf2f(py[(base + c0 + i) * 16384]);
#pragma unroll
    for (int i = 0; i < 16; ++i) {
      float xt = fmaf(vb[i], sc, sh);
      A  = fmaf(uu, A, xt);
      Mx = fmaxf(fmaf(uu, Mx, xt), 0.f);
      Bc *= uu;
    }
  }
  tA[w * 64 + lane] = A; tB[w * 64 + lane] = Bc; tM[w * 64 + lane] = Mx;
  __syncthreads();

  float pA = 0.f, pM = 0.f;
  for (int s = 0; s < w; ++s) {
    float a = tA[s * 64 + lane], b = tB[s * 64 + lane], mm = tM[s * 64 + lane];
    pA = fmaf(b, pA, a);
    pM = fmaxf(fmaf(b, pM, a), mm);
  }
  float h = fmaxf(pA, pM);        // h_start for this segment (h0 = 0)

  unsigned short* ph = hhi + chain;
  for (int c0 = 0; c0 < 64; c0 += 16) {
    float vb[16];
#pragma unroll
    for (int i = 0; i < 16; ++i) vb[i] = bf2f(py[(base + c0 + i) * 16384]);
#pragma unroll
    for (int i = 0; i < 16; ++i) {
      float xt = fmaf(vb[i], sc, sh);
      h = fmaxf(fmaf(uu, h, xt), 0.f);
      ph[(base + c0 + i) * 16384] = f2bf(h);
    }
  }
}

// BN(finalize inline) + IndRNN + residual: y bf16 + x fp32 -> out fp32
__global__ __launch_bounds__(1024, 4)
void k_indrnn_res(const unsigned short* __restrict__ y, const float* __restrict__ x,
                  float* __restrict__ outp,
                  const float* __restrict__ gsum, const float* __restrict__ gsq,
                  const float* __restrict__ g, const float* __restrict__ be,
                  const float* __restrict__ u) {
  __shared__ float tA[1024], tB[1024], tM[1024];
  int lane = threadIdx.x & 63;
  int w = threadIdx.x >> 6;
  int chain = blockIdx.x * 64 + lane;
  int c = chain & 511;
  float m  = gsum[c] * (1.0f / (float)M_DIM);
  float vv = gsq[c]  * (1.0f / (float)M_DIM) - m * m;
  float sc = g[c] * rsqrtf(vv + EPS_BN);
  float sh = be[c] - m * sc;
  float uu = u[c];
  const unsigned short* py = y + chain;
  const float* px = x + chain;
  float* po = outp + chain;
  const int base = w * 64;

  float A = 0.f, Bc = 1.f, Mx = 0.f;
  for (int c0 = 0; c0 < 64; c0 += 16) {
    float vb[16];
#pragma unroll
    for (int i = 0; i < 16; ++i) vb[i] = bf2f(py[(base + c0 + i) * 16384]);
#pragma unroll
    for (int i = 0; i < 16; ++i) {
      float xt = fmaf(vb[i], sc, sh);
      A  = fmaf(uu, A, xt);
      Mx = fmaxf(fmaf(uu, Mx, xt), 0.f);
      Bc *= uu;
    }
  }
  tA[w * 64 + lane] = A; tB[w * 64 + lane] = Bc; tM[w * 64 + lane] = Mx;
  __syncthreads();

  float pA = 0.f, pM = 0.f;
  for (int s = 0; s < w; ++s) {
    float a = tA[s * 64 + lane], b = tB[s * 64 + lane], mm = tM[s * 64 + lane];
    pA = fmaf(b, pA, a);
    pM = fmaxf(fmaf(b, pM, a), mm);
  }
  float h = fmaxf(pA, pM);

  for (int c0 = 0; c0 < 64; c0 += 16) {
    float vb[16], xb[16];
#pragma unroll
    for (int i = 0; i < 16; ++i) vb[i] = bf2f(py[(base + c0 + i) * 16384]);
#pragma unroll
    for (int i = 0; i < 16; ++i) xb[i] = px[(base + c0 + i) * 16384];
#pragma unroll
    for (int i = 0; i < 16; ++i) {
      float xt = fmaf(vb[i], sc, sh);
      h = fmaxf(fmaf(uu, h, xt), 0.f);
      po[(base + c0 + i) * 16384] = h + xb[i];
    }
  }
}

extern "C" void kernel_launch(void* const* d_in, const int* in_sizes, int n_in,
                              void* d_out, int out_size, void* d_ws, size_t ws_size,
                              hipStream_t stream) {
  if (n_in < 11) return;
  const float* x   = (const float*)d_in[0];
  const float* W1  = (const float*)d_in[1];
  const float* b1  = (const float*)d_in[2];
  const float* g1  = (const float*)d_in[3];
  const float* be1 = (const float*)d_in[4];
  const float* u1  = (const float*)d_in[5];
  const float* W2  = (const float*)d_in[6];
  const float* b2  = (const float*)d_in[7];
  const float* g2  = (const float*)d_in[8];
  const float* be2 = (const float*)d_in[9];
  const float* u2  = (const float*)d_in[10];
  float* out = (float*)d_out;

  char* ws = (char*)d_ws;
  const size_t SZ_HALF = (size_t)M_DIM * C_DIM * sizeof(unsigned short); // 33,554,432 B
  const size_t SZ_W    = (size_t)C_DIM * C_DIM * sizeof(unsigned short); //    524,288 B
  unsigned short* Ahi  = (unsigned short*)(ws);                 // x bf16; reused as h1 bf16
  unsigned short* Cbf  = (unsigned short*)(ws + SZ_HALF);       // bf16 y (both GEMMs)
  unsigned short* W1hi = (unsigned short*)(ws + 2 * SZ_HALF);
  unsigned short* W2hi = W1hi + C_DIM * C_DIM;
  float* stats = (float*)(ws + 2 * SZ_HALF + 2 * SZ_W);
  float* sum1 = stats,        *sq1 = stats + 512;
  float* sum2 = stats + 1024, *sq2 = stats + 1536;
  if (ws_size < 2 * SZ_HALF + 2 * SZ_W + 4 * 512 * sizeof(float)) return;

  hipMemsetAsync(stats, 0, 4 * 512 * sizeof(float), stream);

  k_split_all<<<2048, 256, 0, stream>>>(x, W1, W2, Ahi, W1hi, W2hi);

  dim3 gemmGrid(1024);   // 4 blocks/CU
  k_gemm<<<gemmGrid, 256, 0, stream>>>(Ahi, W1hi, b1, Cbf, sum1, sq1);
  k_indrnn_split<<<256, 1024, 0, stream>>>(Cbf, sum1, sq1, g1, be1, u1, Ahi);

  k_gemm<<<gemmGrid, 256, 0, stream>>>(Ahi, W2hi, b2, Cbf, sum2, sq2);
  k_indrnn_res<<<256, 1024, 0, stream>>>(Cbf, x, out, sum2, sq2, g2, be2, u2);
}

// Round 12
// 155.608 us; speedup vs baseline: 1.8997x; 1.0183x over previous
//
#include <hip/hip_runtime.h>
#include <stdint.h>

#define L_DIM 1024
#define N_DIM 32
#define C_DIM 512
#define M_DIM (L_DIM * N_DIM)   // 32768 rows for the GEMMs
#define EPS_BN 1e-5f

typedef __attribute__((ext_vector_type(8))) short bf16x8;
typedef __attribute__((ext_vector_type(4))) float f32x4;

__device__ __forceinline__ unsigned short f2bf(float f) {
  union { float f; unsigned int u; } a; a.f = f;
  unsigned int u = a.u;
  return (unsigned short)((u + 0x7FFFu + ((u >> 16) & 1u)) >> 16); // RNE
}
__device__ __forceinline__ float bf2f(unsigned short h) {
  union { float f; unsigned int u; } a; a.u = ((unsigned int)h) << 16;
  return a.f;
}

__device__ __forceinline__ void gl16(const void* g, void* l) {
  __builtin_amdgcn_global_load_lds(
      (const __attribute__((address_space(1))) unsigned int*)g,
      (__attribute__((address_space(3))) unsigned int*)l, 16, 0, 0);
}

// ---------------- cast fp32 -> bf16 (RNE): x, W1, W2 ----------------
__global__ void k_split_all(const float* __restrict__ x, const float* __restrict__ W1,
                            const float* __restrict__ W2,
                            unsigned short* __restrict__ Ahi,
                            unsigned short* __restrict__ W1hi,
                            unsigned short* __restrict__ W2hi) {
  const int NX = M_DIM * C_DIM / 4;      // 4,194,304 float4
  const int NW = C_DIM * C_DIM / 4;      // 65,536 float4
  int i = blockIdx.x * 256 + threadIdx.x;
  int stride = gridDim.x * 256;
  for (; i < NX + 2 * NW; i += stride) {
    const float4* src; unsigned short* dh; int j;
    if (i < NX)            { src = (const float4*)x;  dh = Ahi;  j = i; }
    else if (i < NX + NW)  { src = (const float4*)W1; dh = W1hi; j = i - NX; }
    else                   { src = (const float4*)W2; dh = W2hi; j = i - NX - NW; }
    float4 v = src[j];
    ushort4 h;
    h.x = f2bf(v.x); h.y = f2bf(v.y); h.z = f2bf(v.z); h.w = f2bf(v.w);
    ((ushort4*)dh)[j] = h;
  }
}

// ---------------- pure-bf16 MFMA GEMM: C(bf16) = A * B^T + bias, fused BN stats ----------------
// A: (M x K) bf16. B: (N x K) bf16 (= W layout). C: (M x N) bf16 (stats from fp32 acc).
// 128x128 tile, BK=64 -> 8 serial rounds (halved from 16: rounds are the cost driver, R10/R11
// evidence). 256 threads = 4 waves (2x2), wave-tile 64x64, 32 MFMA/wave/round.
// Same validated 2-barrier + counted-vmcnt schedule; dbuf 2x32KB LDS -> 2 blocks/CU.
// Grid 1024; XCD swizzle: 32 bm x 4 bn per XCD.
__global__ __launch_bounds__(256, 2)
void k_gemm(const unsigned short* __restrict__ A,
            const unsigned short* __restrict__ B,
            const float* __restrict__ bias, unsigned short* __restrict__ C,
            float* __restrict__ gsum, float* __restrict__ gsq) {
  const int K = C_DIM;
  int d = blockIdx.x;
  int xcd = d & 7;
  int q = d >> 3;                  // 0..127
  int bm = xcd * 32 + (q >> 2);    // 0..255
  int bn = q & 3;                  // 0..3

  // per buffer 32KB = 2048 slots of 16B: A slots [0,1024), B [1024,2048)
  // slot within matrix: s = kc*128 + row, kc 0..7 (8-elem k-chunks of BK=64)
  __shared__ unsigned short lds[2][16384];   // 64 KB total

  int tid  = threadIdx.x;
  int lane = tid & 63;
  int wave = tid >> 6;
  int wm = wave >> 1;              // 0..1
  int wn = wave & 1;               // 0..1
  int lr = lane & 15;
  int lk = lane >> 4;

  f32x4 acc[4][4];
#pragma unroll
  for (int i = 0; i < 4; ++i)
#pragma unroll
    for (int j = 0; j < 4; ++j) acc[i][j] = (f32x4){0.f, 0.f, 0.f, 0.f};

  // staging: thread covers A slots tid+256*i (i=0..3) and B slots tid+256*i (i=0..3)
  const int r0 = tid & 127;
  const int kc0 = tid >> 7;                    // 0..1
  // A slot s = tid + 256*i: row = s&127 = r0, kc = s>>7 = kc0 + 2*i
  const int oa0 = (bm * 128 + r0) * K + (kc0 + 0) * 8;
  const int oa1 = (bm * 128 + r0) * K + (kc0 + 2) * 8;
  const int oa2 = (bm * 128 + r0) * K + (kc0 + 4) * 8;
  const int oa3 = (bm * 128 + r0) * K + (kc0 + 6) * 8;
  const int ob0 = (bn * 128 + r0) * K + (kc0 + 0) * 8;
  const int ob1 = (bn * 128 + r0) * K + (kc0 + 2) * 8;
  const int ob2 = (bn * 128 + r0) * K + (kc0 + 4) * 8;
  const int ob3 = (bn * 128 + r0) * K + (kc0 + 6) * 8;

#define STAGE(buf, kk)                                          \
  do {                                                          \
    unsigned short* Lb = lds[buf];                              \
    gl16(A + oa0 + (kk), Lb + (tid) * 8);                       \
    gl16(A + oa1 + (kk), Lb + (tid + 256) * 8);                 \
    gl16(A + oa2 + (kk), Lb + (tid + 512) * 8);                 \
    gl16(A + oa3 + (kk), Lb + (tid + 768) * 8);                 \
    gl16(B + ob0 + (kk), Lb + (tid + 1024) * 8);                \
    gl16(B + ob1 + (kk), Lb + (tid + 1280) * 8);                \
    gl16(B + ob2 + (kk), Lb + (tid + 1536) * 8);                \
    gl16(B + ob3 + (kk), Lb + (tid + 1792) * 8);                \
  } while (0)

#define COMPUTE(buf)                                                          \
  do {                                                                        \
    const unsigned short* Lb = lds[buf];                                      \
    _Pragma("unroll")                                                         \
    for (int kc2 = 0; kc2 < 2; ++kc2) {                                       \
      bf16x8 bh[4], af[4];                                                    \
      _Pragma("unroll")                                                       \
      for (int nj = 0; nj < 4; ++nj) {                                        \
        int slot = 1024 + (kc2 * 4 + lk) * 128 + wn * 64 + nj * 16 + lr;      \
        bh[nj] = *(const bf16x8*)(Lb + slot * 8);                             \
      }                                                                       \
      _Pragma("unroll")                                                       \
      for (int mi = 0; mi < 4; ++mi) {                                        \
        int slot = (kc2 * 4 + lk) * 128 + wm * 64 + mi * 16 + lr;             \
        af[mi] = *(const bf16x8*)(Lb + slot * 8);                             \
      }                                                                       \
      _Pragma("unroll")                                                       \
      for (int mi = 0; mi < 4; ++mi)                                          \
        _Pragma("unroll")                                                     \
        for (int nj = 0; nj < 4; ++nj)                                        \
          acc[mi][nj] = __builtin_amdgcn_mfma_f32_16x16x32_bf16(af[mi], bh[nj], acc[mi][nj], 0, 0, 0); \
    }                                                                         \
  } while (0)

  const int nt = K >> 6;                       // 8 K-steps of 64
  STAGE(0, 0);
  STAGE(1, 64);                                // 16 loads/thread outstanding

  for (int t = 0; t < nt - 1; ++t) {
    asm volatile("s_waitcnt vmcnt(8)" ::: "memory");  // tile t landed; t+1's 8 in flight
    __builtin_amdgcn_sched_barrier(0);
    __builtin_amdgcn_s_barrier();
    COMPUTE(t & 1);
    __builtin_amdgcn_s_barrier();
    if (t < nt - 2) STAGE(t & 1, (t + 2) << 6);
  }
  asm volatile("s_waitcnt vmcnt(0)" ::: "memory");
  __builtin_amdgcn_sched_barrier(0);
  __builtin_amdgcn_s_barrier();
  COMPUTE((nt - 1) & 1);

  // epilogue: C/D layout col = lane&15, row = (lane>>4)*4 + r; bf16 C + fp32 BN stats
#pragma unroll
  for (int nj = 0; nj < 4; ++nj) {
    int gn = bn * 128 + wn * 64 + nj * 16 + lr;
    float bv = bias[gn];
    float s = 0.f, qq = 0.f;
#pragma unroll
    for (int mi = 0; mi < 4; ++mi) {
      int gm = bm * 128 + wm * 64 + mi * 16 + (lk << 2);
#pragma unroll
      for (int r = 0; r < 4; ++r) {
        float v = acc[mi][nj][r] + bv;
        C[(gm + r) * C_DIM + gn] = f2bf(v);
        s += v; qq += v * v;
      }
    }
    s  += __shfl_xor(s, 16);  qq += __shfl_xor(qq, 16);
    s  += __shfl_xor(s, 32);  qq += __shfl_xor(qq, 32);
    if (lk == 0) {
      atomicAdd(&gsum[gn], s);
      atomicAdd(&gsq[gn], qq);
    }
  }
#undef STAGE
#undef COMPUTE
}

// ---------------- parallel-scan IndRNN (R5 structure, bf16 y input) ----------------
// h_t = max(x_t + u h_{t-1}, 0). Maps h -> max(A + B h, M) form a monoid (B >= 0):
//   (A2,B2,M2) o (A1,B1,M1) = (A2 + B2*A1, B2*B1, max(A2 + B2*M1, M2))
// Block = 1024 threads = 16 waves; wave w owns L-rows [64w,64w+64) of 64 chains (lanes).

// BN(finalize inline) + IndRNN, y bf16 -> h bf16 (GEMM2's A)
__global__ __launch_bounds__(1024, 4)
void k_indrnn_split(const unsigned short* __restrict__ y,
                    const float* __restrict__ gsum, const float* __restrict__ gsq,
                    const float* __restrict__ g, const float* __restrict__ be,
                    const float* __restrict__ u,
                    unsigned short* __restrict__ hhi) {
  __shared__ float tA[1024], tB[1024], tM[1024];
  int lane = threadIdx.x & 63;
  int w = threadIdx.x >> 6;                 // segment 0..15
  int chain = blockIdx.x * 64 + lane;       // (n,c) flat index
  int c = chain & 511;
  float m  = gsum[c] * (1.0f / (float)M_DIM);
  float vv = gsq[c]  * (1.0f / (float)M_DIM) - m * m;
  float sc = g[c] * rsqrtf(vv + EPS_BN);
  float sh = be[c] - m * sc;
  float uu = u[c];
  const unsigned short* py = y + chain;
  const int base = w * 64;

  float A = 0.f, Bc = 1.f, Mx = 0.f;
  for (int c0 = 0; c0 < 64; c0 += 16) {
    float vb[16];
#pragma unroll
    for (int i = 0; i < 16; ++i) vb[i] = bf2f(py[(base + c0 + i) * 16384]);
#pragma unroll
    for (int i = 0; i < 16; ++i) {
      float xt = fmaf(vb[i], sc, sh);
      A  = fmaf(uu, A, xt);
      Mx = fmaxf(fmaf(uu, Mx, xt), 0.f);
      Bc *= uu;
    }
  }
  tA[w * 64 + lane] = A; tB[w * 64 + lane] = Bc; tM[w * 64 + lane] = Mx;
  __syncthreads();

  float pA = 0.f, pM = 0.f;
  for (int s = 0; s < w; ++s) {
    float a = tA[s * 64 + lane], b = tB[s * 64 + lane], mm = tM[s * 64 + lane];
    pA = fmaf(b, pA, a);
    pM = fmaxf(fmaf(b, pM, a), mm);
  }
  float h = fmaxf(pA, pM);        // h_start for this segment (h0 = 0)

  unsigned short* ph = hhi + chain;
  for (int c0 = 0; c0 < 64; c0 += 16) {
    float vb[16];
#pragma unroll
    for (int i = 0; i < 16; ++i) vb[i] = bf2f(py[(base + c0 + i) * 16384]);
#pragma unroll
    for (int i = 0; i < 16; ++i) {
      float xt = fmaf(vb[i], sc, sh);
      h = fmaxf(fmaf(uu, h, xt), 0.f);
      ph[(base + c0 + i) * 16384] = f2bf(h);
    }
  }
}

// BN(finalize inline) + IndRNN + residual: y bf16 + x fp32 -> out fp32
__global__ __launch_bounds__(1024, 4)
void k_indrnn_res(const unsigned short* __restrict__ y, const float* __restrict__ x,
                  float* __restrict__ outp,
                  const float* __restrict__ gsum, const float* __restrict__ gsq,
                  const float* __restrict__ g, const float* __restrict__ be,
                  const float* __restrict__ u) {
  __shared__ float tA[1024], tB[1024], tM[1024];
  int lane = threadIdx.x & 63;
  int w = threadIdx.x >> 6;
  int chain = blockIdx.x * 64 + lane;
  int c = chain & 511;
  float m  = gsum[c] * (1.0f / (float)M_DIM);
  float vv = gsq[c]  * (1.0f / (float)M_DIM) - m * m;
  float sc = g[c] * rsqrtf(vv + EPS_BN);
  float sh = be[c] - m * sc;
  float uu = u[c];
  const unsigned short* py = y + chain;
  const float* px = x + chain;
  float* po = outp + chain;
  const int base = w * 64;

  float A = 0.f, Bc = 1.f, Mx = 0.f;
  for (int c0 = 0; c0 < 64; c0 += 16) {
    float vb[16];
#pragma unroll
    for (int i = 0; i < 16; ++i) vb[i] = bf2f(py[(base + c0 + i) * 16384]);
#pragma unroll
    for (int i = 0; i < 16; ++i) {
      float xt = fmaf(vb[i], sc, sh);
      A  = fmaf(uu, A, xt);
      Mx = fmaxf(fmaf(uu, Mx, xt), 0.f);
      Bc *= uu;
    }
  }
  tA[w * 64 + lane] = A; tB[w * 64 + lane] = Bc; tM[w * 64 + lane] = Mx;
  __syncthreads();

  float pA = 0.f, pM = 0.f;
  for (int s = 0; s < w; ++s) {
    float a = tA[s * 64 + lane], b = tB[s * 64 + lane], mm = tM[s * 64 + lane];
    pA = fmaf(b, pA, a);
    pM = fmaxf(fmaf(b, pM, a), mm);
  }
  float h = fmaxf(pA, pM);

  for (int c0 = 0; c0 < 64; c0 += 16) {
    float vb[16], xb[16];
#pragma unroll
    for (int i = 0; i < 16; ++i) vb[i] = bf2f(py[(base + c0 + i) * 16384]);
#pragma unroll
    for (int i = 0; i < 16; ++i) xb[i] = px[(base + c0 + i) * 16384];
#pragma unroll
    for (int i = 0; i < 16; ++i) {
      float xt = fmaf(vb[i], sc, sh);
      h = fmaxf(fmaf(uu, h, xt), 0.f);
      po[(base + c0 + i) * 16384] = h + xb[i];
    }
  }
}

extern "C" void kernel_launch(void* const* d_in, const int* in_sizes, int n_in,
                              void* d_out, int out_size, void* d_ws, size_t ws_size,
                              hipStream_t stream) {
  if (n_in < 11) return;
  const float* x   = (const float*)d_in[0];
  const float* W1  = (const float*)d_in[1];
  const float* b1  = (const float*)d_in[2];
  const float* g1  = (const float*)d_in[3];
  const float* be1 = (const float*)d_in[4];
  const float* u1  = (const float*)d_in[5];
  const float* W2  = (const float*)d_in[6];
  const float* b2  = (const float*)d_in[7];
  const float* g2  = (const float*)d_in[8];
  const float* be2 = (const float*)d_in[9];
  const float* u2  = (const float*)d_in[10];
  float* out = (float*)d_out;

  char* ws = (char*)d_ws;
  const size_t SZ_HALF = (size_t)M_DIM * C_DIM * sizeof(unsigned short); // 33,554,432 B
  const size_t SZ_W    = (size_t)C_DIM * C_DIM * sizeof(unsigned short); //    524,288 B
  unsigned short* Ahi  = (unsigned short*)(ws);                 // x bf16; reused as h1 bf16
  unsigned short* Cbf  = (unsigned short*)(ws + SZ_HALF);       // bf16 y (both GEMMs)
  unsigned short* W1hi = (unsigned short*)(ws + 2 * SZ_HALF);
  unsigned short* W2hi = W1hi + C_DIM * C_DIM;
  float* stats = (float*)(ws + 2 * SZ_HALF + 2 * SZ_W);
  float* sum1 = stats,        *sq1 = stats + 512;
  float* sum2 = stats + 1024, *sq2 = stats + 1536;
  if (ws_size < 2 * SZ_HALF + 2 * SZ_W + 4 * 512 * sizeof(float)) return;

  hipMemsetAsync(stats, 0, 4 * 512 * sizeof(float), stream);

  k_split_all<<<2048, 256, 0, stream>>>(x, W1, W2, Ahi, W1hi, W2hi);

  dim3 gemmGrid(1024);   // 2 blocks/CU
  k_gemm<<<gemmGrid, 256, 0, stream>>>(Ahi, W1hi, b1, Cbf, sum1, sq1);
  k_indrnn_split<<<256, 1024, 0, stream>>>(Cbf, sum1, sq1, g1, be1, u1, Ahi);

  k_gemm<<<gemmGrid, 256, 0, stream>>>(Ahi, W2hi, b2, Cbf, sum2, sq2);
  k_indrnn_res<<<256, 1024, 0, stream>>>(Cbf, x, out, sum2, sq2, g2, be2, u2);
}

// Round 13
// 152.246 us; speedup vs baseline: 1.9417x; 1.0221x over previous
//
#include <hip/hip_runtime.h>
#include <stdint.h>

#define L_DIM 1024
#define N_DIM 32
#define C_DIM 512
#define M_DIM (L_DIM * N_DIM)   // 32768 rows for the GEMMs
#define EPS_BN 1e-5f

typedef __attribute__((ext_vector_type(8))) short bf16x8;
typedef __attribute__((ext_vector_type(4))) float f32x4;

__device__ __forceinline__ unsigned short f2bf(float f) {
  union { float f; unsigned int u; } a; a.f = f;
  unsigned int u = a.u;
  return (unsigned short)((u + 0x7FFFu + ((u >> 16) & 1u)) >> 16); // RNE
}
__device__ __forceinline__ float bf2f(unsigned short h) {
  union { float f; unsigned int u; } a; a.u = ((unsigned int)h) << 16;
  return a.f;
}

__device__ __forceinline__ void gl16(const void* g, void* l) {
  __builtin_amdgcn_global_load_lds(
      (const __attribute__((address_space(1))) unsigned int*)g,
      (__attribute__((address_space(3))) unsigned int*)l, 16, 0, 0);
}

// ---------------- cast fp32 -> bf16 (RNE): x, W1, W2 ----------------
__global__ void k_split_all(const float* __restrict__ x, const float* __restrict__ W1,
                            const float* __restrict__ W2,
                            unsigned short* __restrict__ Ahi,
                            unsigned short* __restrict__ W1hi,
                            unsigned short* __restrict__ W2hi) {
  const int NX = M_DIM * C_DIM / 4;      // 4,194,304 float4
  const int NW = C_DIM * C_DIM / 4;      // 65,536 float4
  int i = blockIdx.x * 256 + threadIdx.x;
  int stride = gridDim.x * 256;
  for (; i < NX + 2 * NW; i += stride) {
    const float4* src; unsigned short* dh; int j;
    if (i < NX)            { src = (const float4*)x;  dh = Ahi;  j = i; }
    else if (i < NX + NW)  { src = (const float4*)W1; dh = W1hi; j = i - NX; }
    else                   { src = (const float4*)W2; dh = W2hi; j = i - NX - NW; }
    float4 v = src[j];
    ushort4 h;
    h.x = f2bf(v.x); h.y = f2bf(v.y); h.z = f2bf(v.z); h.w = f2bf(v.w);
    ((ushort4*)dh)[j] = h;
  }
}

// ---------------- pure-bf16 MFMA GEMM: C(bf16) = A * B^T + bias, fused BN stats ----------------
// A: (M x K) bf16. B: (N x K) bf16. C: (M x N) bf16 (stats from fp32 acc).
// 128x128 tile, BK=64, 8 rounds; 256 threads = 4 waves (2x2), wave-tile 64x64.
// R5-validated 2-barrier + counted-vmcnt schedule; dbuf 2x32KB LDS -> 2 blocks/CU.
// NEW (R13): epilogue stages fp32 tile through LDS -> bf16x8 coalesced 16B stores
// (replaces 64 scalar 2B stores/thread that dominated as a config-invariant ~30us).
__global__ __launch_bounds__(256, 2)
void k_gemm(const unsigned short* __restrict__ A,
            const unsigned short* __restrict__ B,
            const float* __restrict__ bias, unsigned short* __restrict__ C,
            float* __restrict__ gsum, float* __restrict__ gsq) {
  const int K = C_DIM;
  int d = blockIdx.x;
  int xcd = d & 7;
  int q = d >> 3;                  // 0..127
  int bm = xcd * 32 + (q >> 2);    // 0..255
  int bn = q & 3;                  // 0..3

  // per buffer 32KB = 2048 slots of 16B: A slots [0,1024), B [1024,2048)
  // slot within matrix: s = kc*128 + row, kc 0..7 (8-elem k-chunks of BK=64)
  __shared__ unsigned short lds[2][16384];   // 64 KB total; reused as 128x128 f32 tile in epilogue

  int tid  = threadIdx.x;
  int lane = tid & 63;
  int wave = tid >> 6;
  int wm = wave >> 1;              // 0..1
  int wn = wave & 1;               // 0..1
  int lr = lane & 15;
  int lk = lane >> 4;

  f32x4 acc[4][4];
#pragma unroll
  for (int i = 0; i < 4; ++i)
#pragma unroll
    for (int j = 0; j < 4; ++j) acc[i][j] = (f32x4){0.f, 0.f, 0.f, 0.f};

  const int r0 = tid & 127;
  const int kc0 = tid >> 7;                    // 0..1
  const int oa0 = (bm * 128 + r0) * K + (kc0 + 0) * 8;
  const int oa1 = (bm * 128 + r0) * K + (kc0 + 2) * 8;
  const int oa2 = (bm * 128 + r0) * K + (kc0 + 4) * 8;
  const int oa3 = (bm * 128 + r0) * K + (kc0 + 6) * 8;
  const int ob0 = (bn * 128 + r0) * K + (kc0 + 0) * 8;
  const int ob1 = (bn * 128 + r0) * K + (kc0 + 2) * 8;
  const int ob2 = (bn * 128 + r0) * K + (kc0 + 4) * 8;
  const int ob3 = (bn * 128 + r0) * K + (kc0 + 6) * 8;

#define STAGE(buf, kk)                                          \
  do {                                                          \
    unsigned short* Lb = lds[buf];                              \
    gl16(A + oa0 + (kk), Lb + (tid) * 8);                       \
    gl16(A + oa1 + (kk), Lb + (tid + 256) * 8);                 \
    gl16(A + oa2 + (kk), Lb + (tid + 512) * 8);                 \
    gl16(A + oa3 + (kk), Lb + (tid + 768) * 8);                 \
    gl16(B + ob0 + (kk), Lb + (tid + 1024) * 8);                \
    gl16(B + ob1 + (kk), Lb + (tid + 1280) * 8);                \
    gl16(B + ob2 + (kk), Lb + (tid + 1536) * 8);                \
    gl16(B + ob3 + (kk), Lb + (tid + 1792) * 8);                \
  } while (0)

#define COMPUTE(buf)                                                          \
  do {                                                                        \
    const unsigned short* Lb = lds[buf];                                      \
    _Pragma("unroll")                                                         \
    for (int kc2 = 0; kc2 < 2; ++kc2) {                                       \
      bf16x8 bh[4], af[4];                                                    \
      _Pragma("unroll")                                                       \
      for (int nj = 0; nj < 4; ++nj) {                                        \
        int slot = 1024 + (kc2 * 4 + lk) * 128 + wn * 64 + nj * 16 + lr;      \
        bh[nj] = *(const bf16x8*)(Lb + slot * 8);                             \
      }                                                                       \
      _Pragma("unroll")                                                       \
      for (int mi = 0; mi < 4; ++mi) {                                        \
        int slot = (kc2 * 4 + lk) * 128 + wm * 64 + mi * 16 + lr;             \
        af[mi] = *(const bf16x8*)(Lb + slot * 8);                             \
      }                                                                       \
      _Pragma("unroll")                                                       \
      for (int mi = 0; mi < 4; ++mi)                                          \
        _Pragma("unroll")                                                     \
        for (int nj = 0; nj < 4; ++nj)                                        \
          acc[mi][nj] = __builtin_amdgcn_mfma_f32_16x16x32_bf16(af[mi], bh[nj], acc[mi][nj], 0, 0, 0); \
    }                                                                         \
  } while (0)

  const int nt = K >> 6;                       // 8 K-steps of 64
  STAGE(0, 0);
  STAGE(1, 64);                                // 16 loads/thread outstanding

  for (int t = 0; t < nt - 1; ++t) {
    asm volatile("s_waitcnt vmcnt(8)" ::: "memory");  // tile t landed; t+1's 8 in flight
    __builtin_amdgcn_sched_barrier(0);
    __builtin_amdgcn_s_barrier();
    COMPUTE(t & 1);
    __builtin_amdgcn_s_barrier();
    if (t < nt - 2) STAGE(t & 1, (t + 2) << 6);
  }
  asm volatile("s_waitcnt vmcnt(0)" ::: "memory");
  __builtin_amdgcn_sched_barrier(0);
  __builtin_amdgcn_s_barrier();
  COMPUTE((nt - 1) & 1);

  // ---- epilogue (R13): fp32 tile -> LDS, stats shfl+atomic, coalesced bf16 store ----
  __syncthreads();                              // all waves done reading K-loop LDS
  float* T = (float*)&lds[0][0];                // 128x128 f32 tile, row-major 512B/row
#pragma unroll
  for (int nj = 0; nj < 4; ++nj) {
    int gn = bn * 128 + wn * 64 + nj * 16 + lr;
    float bv = bias[gn];
    float s = 0.f, qq = 0.f;
    int lcol = wn * 64 + nj * 16 + lr;
#pragma unroll
    for (int mi = 0; mi < 4; ++mi) {
      int lrow = wm * 64 + mi * 16 + (lk << 2);
#pragma unroll
      for (int r = 0; r < 4; ++r) {
        float v = acc[mi][nj][r] + bv;
        T[(lrow + r) * 128 + lcol] = v;
        s += v; qq += v * v;
      }
    }
    s  += __shfl_xor(s, 16);  qq += __shfl_xor(qq, 16);
    s  += __shfl_xor(s, 32);  qq += __shfl_xor(qq, 32);
    if (lk == 0) {
      atomicAdd(&gsum[gn], s);
      atomicAdd(&gsq[gn], qq);
    }
  }
  __syncthreads();
  // each thread: 8 iters x (32B LDS read -> bf16x8 pack -> 16B global store)
  {
    int rr = tid >> 4, jj = tid & 15;
#pragma unroll
    for (int i = 0; i < 8; ++i) {
      int row = i * 16 + rr;
      const float* src = T + row * 128 + jj * 8;
      f32x4 a0 = *(const f32x4*)src;
      f32x4 a1 = *(const f32x4*)(src + 4);
      union { unsigned int u[4]; bf16x8 v; } P;
      P.u[0] = (unsigned int)f2bf(a0[0]) | ((unsigned int)f2bf(a0[1]) << 16);
      P.u[1] = (unsigned int)f2bf(a0[2]) | ((unsigned int)f2bf(a0[3]) << 16);
      P.u[2] = (unsigned int)f2bf(a1[0]) | ((unsigned int)f2bf(a1[1]) << 16);
      P.u[3] = (unsigned int)f2bf(a1[2]) | ((unsigned int)f2bf(a1[3]) << 16);
      *(bf16x8*)(C + (size_t)(bm * 128 + row) * C_DIM + bn * 128 + jj * 8) = P.v;
    }
  }
#undef STAGE
#undef COMPUTE
}

// ---------------- parallel-scan IndRNN (R5 structure, bf16 y input) ----------------
// h_t = max(x_t + u h_{t-1}, 0). Maps h -> max(A + B h, M) form a monoid (B >= 0):
//   (A2,B2,M2) o (A1,B1,M1) = (A2 + B2*A1, B2*B1, max(A2 + B2*M1, M2))
// Block = 1024 threads = 16 waves; wave w owns L-rows [64w,64w+64) of 64 chains (lanes).

// BN(finalize inline) + IndRNN, y bf16 -> h bf16 (GEMM2's A)
__global__ __launch_bounds__(1024, 4)
void k_indrnn_split(const unsigned short* __restrict__ y,
                    const float* __restrict__ gsum, const float* __restrict__ gsq,
                    const float* __restrict__ g, const float* __restrict__ be,
                    const float* __restrict__ u,
                    unsigned short* __restrict__ hhi) {
  __shared__ float tA[1024], tB[1024], tM[1024];
  int lane = threadIdx.x & 63;
  int w = threadIdx.x >> 6;                 // segment 0..15
  int chain = blockIdx.x * 64 + lane;       // (n,c) flat index
  int c = chain & 511;
  float m  = gsum[c] * (1.0f / (float)M_DIM);
  float vv = gsq[c]  * (1.0f / (float)M_DIM) - m * m;
  float sc = g[c] * rsqrtf(vv + EPS_BN);
  float sh = be[c] - m * sc;
  float uu = u[c];
  const unsigned short* py = y + chain;
  const int base = w * 64;

  float A = 0.f, Bc = 1.f, Mx = 0.f;
  for (int c0 = 0; c0 < 64; c0 += 16) {
    float vb[16];
#pragma unroll
    for (int i = 0; i < 16; ++i) vb[i] = bf2f(py[(base + c0 + i) * 16384]);
#pragma unroll
    for (int i = 0; i < 16; ++i) {
      float xt = fmaf(vb[i], sc, sh);
      A  = fmaf(uu, A, xt);
      Mx = fmaxf(fmaf(uu, Mx, xt), 0.f);
      Bc *= uu;
    }
  }
  tA[w * 64 + lane] = A; tB[w * 64 + lane] = Bc; tM[w * 64 + lane] = Mx;
  __syncthreads();

  float pA = 0.f, pM = 0.f;
  for (int s = 0; s < w; ++s) {
    float a = tA[s * 64 + lane], b = tB[s * 64 + lane], mm = tM[s * 64 + lane];
    pA = fmaf(b, pA, a);
    pM = fmaxf(fmaf(b, pM, a), mm);
  }
  float h = fmaxf(pA, pM);        // h_start for this segment (h0 = 0)

  unsigned short* ph = hhi + chain;
  for (int c0 = 0; c0 < 64; c0 += 16) {
    float vb[16];
#pragma unroll
    for (int i = 0; i < 16; ++i) vb[i] = bf2f(py[(base + c0 + i) * 16384]);
#pragma unroll
    for (int i = 0; i < 16; ++i) {
      float xt = fmaf(vb[i], sc, sh);
      h = fmaxf(fmaf(uu, h, xt), 0.f);
      ph[(base + c0 + i) * 16384] = f2bf(h);
    }
  }
}

// BN(finalize inline) + IndRNN + residual: y bf16 + x fp32 -> out fp32
__global__ __launch_bounds__(1024, 4)
void k_indrnn_res(const unsigned short* __restrict__ y, const float* __restrict__ x,
                  float* __restrict__ outp,
                  const float* __restrict__ gsum, const float* __restrict__ gsq,
                  const float* __restrict__ g, const float* __restrict__ be,
                  const float* __restrict__ u) {
  __shared__ float tA[1024], tB[1024], tM[1024];
  int lane = threadIdx.x & 63;
  int w = threadIdx.x >> 6;
  int chain = blockIdx.x * 64 + lane;
  int c = chain & 511;
  float m  = gsum[c] * (1.0f / (float)M_DIM);
  float vv = gsq[c]  * (1.0f / (float)M_DIM) - m * m;
  float sc = g[c] * rsqrtf(vv + EPS_BN);
  float sh = be[c] - m * sc;
  float uu = u[c];
  const unsigned short* py = y + chain;
  const float* px = x + chain;
  float* po = outp + chain;
  const int base = w * 64;

  float A = 0.f, Bc = 1.f, Mx = 0.f;
  for (int c0 = 0; c0 < 64; c0 += 16) {
    float vb[16];
#pragma unroll
    for (int i = 0; i < 16; ++i) vb[i] = bf2f(py[(base + c0 + i) * 16384]);
#pragma unroll
    for (int i = 0; i < 16; ++i) {
      float xt = fmaf(vb[i], sc, sh);
      A  = fmaf(uu, A, xt);
      Mx = fmaxf(fmaf(uu, Mx, xt), 0.f);
      Bc *= uu;
    }
  }
  tA[w * 64 + lane] = A; tB[w * 64 + lane] = Bc; tM[w * 64 + lane] = Mx;
  __syncthreads();

  float pA = 0.f, pM = 0.f;
  for (int s = 0; s < w; ++s) {
    float a = tA[s * 64 + lane], b = tB[s * 64 + lane], mm = tM[s * 64 + lane];
    pA = fmaf(b, pA, a);
    pM = fmaxf(fmaf(b, pM, a), mm);
  }
  float h = fmaxf(pA, pM);

  for (int c0 = 0; c0 < 64; c0 += 16) {
    float vb[16], xb[16];
#pragma unroll
    for (int i = 0; i < 16; ++i) vb[i] = bf2f(py[(base + c0 + i) * 16384]);
#pragma unroll
    for (int i = 0; i < 16; ++i) xb[i] = px[(base + c0 + i) * 16384];
#pragma unroll
    for (int i = 0; i < 16; ++i) {
      float xt = fmaf(vb[i], sc, sh);
      h = fmaxf(fmaf(uu, h, xt), 0.f);
      po[(base + c0 + i) * 16384] = h + xb[i];
    }
  }
}

extern "C" void kernel_launch(void* const* d_in, const int* in_sizes, int n_in,
                              void* d_out, int out_size, void* d_ws, size_t ws_size,
                              hipStream_t stream) {
  if (n_in < 11) return;
  const float* x   = (const float*)d_in[0];
  const float* W1  = (const float*)d_in[1];
  const float* b1  = (const float*)d_in[2];
  const float* g1  = (const float*)d_in[3];
  const float* be1 = (const float*)d_in[4];
  const float* u1  = (const float*)d_in[5];
  const float* W2  = (const float*)d_in[6];
  const float* b2  = (const float*)d_in[7];
  const float* g2  = (const float*)d_in[8];
  const float* be2 = (const float*)d_in[9];
  const float* u2  = (const float*)d_in[10];
  float* out = (float*)d_out;

  char* ws = (char*)d_ws;
  const size_t SZ_HALF = (size_t)M_DIM * C_DIM * sizeof(unsigned short); // 33,554,432 B
  const size_t SZ_W    = (size_t)C_DIM * C_DIM * sizeof(unsigned short); //    524,288 B
  unsigned short* Ahi  = (unsigned short*)(ws);                 // x bf16; reused as h1 bf16
  unsigned short* Cbf  = (unsigned short*)(ws + SZ_HALF);       // bf16 y (both GEMMs)
  unsigned short* W1hi = (unsigned short*)(ws + 2 * SZ_HALF);
  unsigned short* W2hi = W1hi + C_DIM * C_DIM;
  float* stats = (float*)(ws + 2 * SZ_HALF + 2 * SZ_W);
  float* sum1 = stats,        *sq1 = stats + 512;
  float* sum2 = stats + 1024, *sq2 = stats + 1536;
  if (ws_size < 2 * SZ_HALF + 2 * SZ_W + 4 * 512 * sizeof(float)) return;

  hipMemsetAsync(stats, 0, 4 * 512 * sizeof(float), stream);

  k_split_all<<<2048, 256, 0, stream>>>(x, W1, W2, Ahi, W1hi, W2hi);

  dim3 gemmGrid(1024);   // 2 blocks/CU
  k_gemm<<<gemmGrid, 256, 0, stream>>>(Ahi, W1hi, b1, Cbf, sum1, sq1);
  k_indrnn_split<<<256, 1024, 0, stream>>>(Cbf, sum1, sq1, g1, be1, u1, Ahi);

  k_gemm<<<gemmGrid, 256, 0, stream>>>(Ahi, W2hi, b2, Cbf, sum2, sq2);
  k_indrnn_res<<<256, 1024, 0, stream>>>(Cbf, x, out, sum2, sq2, g2, be2, u2);
}